// Round 15
// baseline (819.413 us; speedup 1.0000x reference)
//
#include <hip/hip_runtime.h>
#include <hip/hip_bf16.h>
#include <math.h>

#define NN 8192
#define EE 131072
#define HH 256
#define LL 3
#define RR 128
#define NGG 64
#define MSG_WAVES 16         // waves per k_msg block (1024 threads)

typedef __attribute__((ext_vector_type(8))) short bf16x8;
typedef __attribute__((ext_vector_type(4))) float f32x4;
typedef __attribute__((ext_vector_type(2))) float f32x2;
typedef unsigned short u16;

union U4 { ushort4 v; unsigned short a[4]; };
union U8 { uint4 v; unsigned short a[8]; };

__device__ __forceinline__ float silu(float v) { return v / (1.0f + expf(-v)); }
__device__ __forceinline__ float b2f(unsigned short u) { return __uint_as_float(((unsigned)u) << 16); }
__device__ __forceinline__ unsigned short f2b(float f) {
    unsigned u = __float_as_uint(f);
    u += 0x7fff + ((u >> 16) & 1);
    return (unsigned short)(u >> 16);
}

constexpr float kInvSqrt2 = 0.70710678118654752440f;
constexpr float kInvSqrt3 = 0.57735026918962576451f;
constexpr float kInvSqrtH = 0.0625f; // 1/sqrt(256)

// ---------------- utility ----------------
__global__ void k_zero(float* __restrict__ p, int n4) {
    int i = blockIdx.x * 256 + threadIdx.x;
    if (i < n4) ((float4*)p)[i] = make_float4(0.f, 0.f, 0.f, 0.f);
}

// ---------------- ALL weight prep in one launch ----------------
// transpose in[K,N] fp32 -> out[N,K] bf16; rbf_w: row-pair interleaved k-major bf16
// rbf layout: dst[(k>>1)*1536 + n*2 + (k&1)]  (16B paired LDS reads in k_msg)
__global__ __launch_bounds__(256) void k_wt_all(
    const float* __restrict__ xp_w1, const float* __restrict__ xp_w2,
    const float* __restrict__ rbf_w, const float* __restrict__ vec_w,
    const float* __restrict__ xv_w1, const float* __restrict__ xv_w2,
    const float* __restrict__ oe_w1,
    u16* __restrict__ xp_w1T, u16* __restrict__ xp_w2T, u16* __restrict__ rbf_wP,
    u16* __restrict__ vec_wT, u16* __restrict__ xv_w1T, u16* __restrict__ xv_w2T,
    u16* __restrict__ oe_w1T) {
    int bid = blockIdx.x;
    const float* src; u16* dst; int K, N, t, pairmode = 0;
    if (bid < 2400) {
        int l = bid / 800, r = bid % 800;
        if (r < 64)       { src = xp_w1 + (size_t)l * 65536;  dst = xp_w1T + (size_t)l * 65536;  K = 256; N = 256; t = r; }
        else if (r < 256) { src = xp_w2 + (size_t)l * 196608; dst = xp_w2T + (size_t)l * 196608; K = 256; N = 768; t = r - 64; }
        else if (r < 352) { src = rbf_w + (size_t)l * 98304;  dst = rbf_wP + (size_t)l * 98304;  K = 128; N = 768; t = r - 256; pairmode = 1; }
        else if (r < 480) { src = vec_w + (size_t)l * 131072; dst = vec_wT + (size_t)l * 131072; K = 256; N = 512; t = r - 352; }
        else if (r < 608) { src = xv_w1 + (size_t)l * 131072; dst = xv_w1T + (size_t)l * 131072; K = 512; N = 256; t = r - 480; }
        else              { src = xv_w2 + (size_t)l * 196608; dst = xv_w2T + (size_t)l * 196608; K = 256; N = 768; t = r - 608; }
    } else {
        src = oe_w1; dst = oe_w1T; K = 256; N = 128; t = bid - 2400;
    }
    int nx = N >> 5;
    int bn = (t % nx) * 32, bk = (t / nx) * 32;
    int tx = threadIdx.x & 31, ty = threadIdx.x >> 5;   // 32 x 8
    if (pairmode) {
#pragma unroll
        for (int i = 0; i < 32; i += 8) {
            int k = bk + ty + i, n = bn + tx;
            dst[(size_t)(k >> 1) * 1536 + n * 2 + (k & 1)] = f2b(src[(size_t)k * N + n]);
        }
        return;
    }
    __shared__ float tile[32][33];
#pragma unroll
    for (int i = 0; i < 32; i += 8)
        tile[ty + i][tx] = src[(size_t)(bk + ty + i) * N + bn + tx];
    __syncthreads();
#pragma unroll
    for (int i = 0; i < 32; i += 8)
        dst[(size_t)(bn + ty + i) * K + bk + tx] = f2b(tile[tx][ty + i]);
}

// ---------------- init: x = atom_emb[z], + LayerNorm(ln[0]) -> xlnb ----------------
__global__ void k_init_ln(const float* __restrict__ emb, const int* __restrict__ z,
                          const float* __restrict__ w, const float* __restrict__ b,
                          float* __restrict__ x, u16* __restrict__ xlnb) {
    int n = blockIdx.x, t = threadIdx.x;
    float v = emb[z[n] * HH + t];
    x[(size_t)n * HH + t] = v;
    float s = v, q = v * v;
#pragma unroll
    for (int m = 32; m >= 1; m >>= 1) {
        s += __shfl_xor(s, m, 64);
        q += __shfl_xor(q, m, 64);
    }
    __shared__ float s_sum[4], s_sq[4];
    int wid = t >> 6;
    if ((t & 63) == 0) { s_sum[wid] = s; s_sq[wid] = q; }
    __syncthreads();
    float S = s_sum[0] + s_sum[1] + s_sum[2] + s_sum[3];
    float Q = s_sq[0] + s_sq[1] + s_sq[2] + s_sq[3];
    float mu = S * (1.0f / HH);
    float var = Q * (1.0f / HH) - mu * mu;
    float rs = rsqrtf(var + 1e-5f);
    xlnb[(size_t)n * HH + t] = f2b((v - mu) * rs * w[t] + b[t]);
}

// ---------------- edge geometry + degree histogram (fused) ----------------
__global__ void k_geom_hist(const float* __restrict__ pos, const int* __restrict__ ei,
                            float* __restrict__ ev, int* __restrict__ deg) {
    int e = blockIdx.x * 256 + threadIdx.x;
    if (e >= EE) return;
    int s = ei[e], d = ei[EE + e];
    float rx = pos[s * 3 + 0] - pos[d * 3 + 0];
    float ry = pos[s * 3 + 1] - pos[d * 3 + 1];
    float rz = pos[s * 3 + 2] - pos[d * 3 + 2];
    float dist = sqrtf(rx * rx + ry * ry + rz * rz);
    float inv = 1.0f / dist;
    ((float4*)ev)[e] = make_float4(rx * inv, ry * inv, rz * inv, dist);
    atomicAdd(&deg[d], 1);
}

// ---------------- scan (CSR row_ptr) + degree bucket-sort, one block ---------------
__global__ void k_scan_sort(const int* __restrict__ deg, int* __restrict__ row_ptr,
                            int* __restrict__ fill, int* __restrict__ dorder) {
    __shared__ int buf[256];
    __shared__ int carry_s;
    int t = threadIdx.x;
    if (t == 0) carry_s = 0;
    __syncthreads();
    for (int r = 0; r < NN; r += 256) {
        int v = deg[r + t];
        buf[t] = v;
        __syncthreads();
        for (int ofs = 1; ofs < 256; ofs <<= 1) {
            int add = (t >= ofs) ? buf[t - ofs] : 0;
            __syncthreads();
            buf[t] += add;
            __syncthreads();
        }
        int excl = buf[t] - v;
        int carry = carry_s;
        row_ptr[r + t] = carry + excl;
        fill[r + t] = carry + excl;
        __syncthreads();
        if (t == 255) carry_s = carry + buf[t];
        __syncthreads();
    }
    if (t == 0) row_ptr[NN] = carry_s;
    __syncthreads();
    // ---- bucket sort by degree, descending ----
    __shared__ int bins[256];
    __shared__ int base[256];
    bins[t] = 0;
    __syncthreads();
    for (int d = t; d < NN; d += 256) {
        int b = deg[d]; b = b > 255 ? 255 : b;
        atomicAdd(&bins[b], 1);
    }
    __syncthreads();
    if (t == 0) {
        int acc = 0;
        for (int k = 255; k >= 0; --k) { base[k] = acc; acc += bins[k]; }
    }
    __syncthreads();
    bins[t] = 0;
    __syncthreads();
    for (int d = t; d < NN; d += 256) {
        int b = deg[d]; b = b > 255 ? 255 : b;
        int p = atomicAdd(&bins[b], 1);
        dorder[base[b] + p] = d;
    }
}

// scatter + fused per-edge gaussian window (8 rows, EVEN-aligned k0, clamp [0,120])
__global__ void k_scatter(const int* __restrict__ ei, const float* __restrict__ ev,
                          int* __restrict__ fill, int* __restrict__ srcp,
                          float4* __restrict__ evp, int* __restrict__ k0tab,
                          float* __restrict__ gtab) {
    int e = blockIdx.x * 256 + threadIdx.x;
    if (e >= EE) return;
    int d = ei[EE + e];
    int pos = atomicAdd(&fill[d], 1);
    float4 e4 = ((const float4*)ev)[e];
    srcp[pos] = ei[e];
    evp[pos] = e4;
    const float step = 12.0f / 127.0f;
    const float coeff = -0.5f / (step * step);
    float dist = e4.w;
    int k0 = ((int)floorf(dist / step) - 3) & ~1;   // even-aligned
    k0 = k0 < 0 ? 0 : (k0 > 120 ? 120 : k0);
    float g[8];
#pragma unroll
    for (int k = 0; k < 8; ++k) {
        float t = dist - (k0 + k) * step;
        g[k] = expf(coeff * t * t);
    }
    k0tab[pos] = k0;
    ((float4*)gtab)[pos * 2 + 0] = make_float4(g[0], g[1], g[2], g[3]);
    ((float4*)gtab)[pos * 2 + 1] = make_float4(g[4], g[5], g[6], g[7]);
}

// ---------------- bf16 MFMA GEMM: C = act(A[M,K] @ BT[N,K]^T + bias) ----------------
template <int AF32, int OUT_BF16, int ACT>
__global__ __launch_bounds__(256) void k_gemm(
    const void* __restrict__ Av, const u16* __restrict__ BT,
    const float* __restrict__ bias, void* __restrict__ C, int M, int K, int N) {
    __shared__ uint4 As4[512];
    __shared__ uint4 Bs4[512];
    u16* As = (u16*)As4;
    u16* Bs = (u16*)Bs4;
    int tid = threadIdx.x;
    int wave = tid >> 6, lane = tid & 63;
    int bm = blockIdx.y * 128, bn = blockIdx.x * 128;
    int wm = (wave >> 1) * 64, wn = (wave & 1) * 64;
    int lm = lane & 15;
    int kg = lane >> 4;
    f32x4 acc[4][4] = {};

    for (int k0 = 0; k0 < K; k0 += 32) {
#pragma unroll
        for (int it = 0; it < 2; ++it) {
            int idx = it * 256 + tid;
            int r = idx >> 2, seg = idx & 3;
            if (AF32) {
                const float* Af = (const float*)Av;
                float4 fa = *(const float4*)&Af[(size_t)(bm + r) * K + k0 + seg * 8];
                float4 fb = *(const float4*)&Af[(size_t)(bm + r) * K + k0 + seg * 8 + 4];
                U8 u;
                u.a[0] = f2b(fa.x); u.a[1] = f2b(fa.y); u.a[2] = f2b(fa.z); u.a[3] = f2b(fa.w);
                u.a[4] = f2b(fb.x); u.a[5] = f2b(fb.y); u.a[6] = f2b(fb.z); u.a[7] = f2b(fb.w);
                As4[idx] = u.v;
            } else {
                const u16* A = (const u16*)Av;
                As4[idx] = *(const uint4*)&A[(size_t)(bm + r) * K + k0 + seg * 8];
            }
            Bs4[idx] = *(const uint4*)&BT[(size_t)(bn + r) * K + k0 + seg * 8];
        }
        __syncthreads();
        bf16x8 af[4], bfr[4];
#pragma unroll
        for (int i = 0; i < 4; ++i)
            af[i] = *(const bf16x8*)&As[(wm + i * 16 + lm) * 32 + kg * 8];
#pragma unroll
        for (int j = 0; j < 4; ++j)
            bfr[j] = *(const bf16x8*)&Bs[(wn + j * 16 + lm) * 32 + kg * 8];
#pragma unroll
        for (int i = 0; i < 4; ++i)
#pragma unroll
            for (int j = 0; j < 4; ++j)
                acc[i][j] = __builtin_amdgcn_mfma_f32_16x16x32_bf16(af[i], bfr[j], acc[i][j], 0, 0, 0);
        __syncthreads();
    }

#pragma unroll
    for (int j = 0; j < 4; ++j) {
        int col = bn + wn + j * 16 + lm;
        float bv = bias ? bias[col] : 0.f;
#pragma unroll
        for (int i = 0; i < 4; ++i) {
            int row0 = bm + wm + i * 16 + kg * 4;
#pragma unroll
            for (int r = 0; r < 4; ++r) {
                float v = acc[i][j][r] + bv;
                if (ACT) v = silu(v);
                if (OUT_BF16)
                    ((u16*)C)[(size_t)(row0 + r) * N + col] = f2b(v);
                else
                    ((float*)C)[(size_t)(row0 + r) * N + col] = v;
            }
        }
    }
}

// ---------------- fused message pass v10: paired-row panel + packed-f32 math -------
// 16-wave blocks, degree-sorted dsts (R14 winner). W panel row-pair interleaved:
// 4 x ds_read_b128 per edge-pass (was 8 x b64); combine/accumulate in f32x2 so the
// compiler can emit v_pk_fma_f32 (2 FMAs/inst).
__global__ __launch_bounds__(1024) void k_msg(
    const u16* __restrict__ xhb, const u16* __restrict__ vinb,
    const int* __restrict__ srcp, const float4* __restrict__ evp,
    const int* __restrict__ row_ptr, const int* __restrict__ k0tab,
    const float* __restrict__ gtab, const u16* __restrict__ WP /*pair-interleaved*/,
    const float* __restrict__ rbias, float* __restrict__ x,
    const float* __restrict__ vin, float* __restrict__ vecM,
    const int* __restrict__ dorder) {
    __shared__ u16 Wp[64 * 512];    // 64 KB panel: [64 row-pairs][256 cols][2]
    int tid = threadIdx.x;
    int wave = tid >> 6, lane = tid & 63;
    int c0 = lane * 4;
    int d = dorder[blockIdx.x * MSG_WAVES + wave];
    int E0 = row_ptr[d], E1 = row_ptr[d + 1];
    f32x2 accvA[3] = {};            // cols c0,c0+1 ; persists panels 1,2
    f32x2 accvB[3] = {};            // cols c0+2,c0+3

#pragma unroll
    for (int p = 0; p < 3; ++p) {
        __syncthreads();
#pragma unroll
        for (int it = 0; it < 4; ++it) {        // cooperative 64KB panel load
            int idx = it * 1024 + tid;          // 4096 uint4
            int r = idx >> 6;                   // 64 row-pairs, 64 uint4/row
            int c8 = (idx & 63) * 8;
            *(uint4*)&Wp[r * 512 + c8] =
                *(const uint4*)&WP[(size_t)r * 1536 + p * 512 + c8];
        }
        __syncthreads();
        float4 bb = ((const float4*)(rbias + p * 256))[lane];
        f32x2 accxA = {}, accxB = {};
        for (int j = E0; j < E1; ++j) {
            int s = srcp[j];
            int kp = k0tab[j] >> 1;             // even-aligned pair index
            float4 ga = ((const float4*)gtab)[(size_t)j * 2 + 0];
            float4 gb = ((const float4*)gtab)[(size_t)j * 2 + 1];
            float g[8] = {ga.x, ga.y, ga.z, ga.w, gb.x, gb.y, gb.z, gb.w};
            f32x2 rrA = {bb.x, bb.y};
            f32x2 rrB = {bb.z, bb.w};
#pragma unroll
            for (int p2 = 0; p2 < 4; ++p2) {
                U8 w;
                w.v = *(const uint4*)&Wp[(kp + p2) * 512 + c0 * 2];  // ds_read_b128
                float ge = g[2 * p2], go = g[2 * p2 + 1];
                f32x2 loA = {b2f(w.a[0]), b2f(w.a[2])};
                f32x2 hiA = {b2f(w.a[1]), b2f(w.a[3])};
                f32x2 loB = {b2f(w.a[4]), b2f(w.a[6])};
                f32x2 hiB = {b2f(w.a[5]), b2f(w.a[7])};
                rrA += ge * loA + go * hiA;
                rrB += ge * loB + go * hiB;
            }
            if (p == 0) {
                U4 X; X.v = *(const ushort4*)(xhb + (size_t)s * 768 + c0);
                f32x2 xA = {b2f(X.a[0]), b2f(X.a[1])};
                f32x2 xB = {b2f(X.a[2]), b2f(X.a[3])};
                accxA += xA * rrA;
                accxB += xB * rrB;
            } else if (p == 1) {
                U4 X, V0, V1, V2;
                X.v = *(const ushort4*)(xhb + (size_t)s * 768 + 256 + c0);
                V0.v = *(const ushort4*)(vinb + (size_t)s * 768 + c0);
                V1.v = *(const ushort4*)(vinb + (size_t)s * 768 + 256 + c0);
                V2.v = *(const ushort4*)(vinb + (size_t)s * 768 + 512 + c0);
                f32x2 m1A = f32x2{b2f(X.a[0]), b2f(X.a[1])} * rrA * kInvSqrt3;
                f32x2 m1B = f32x2{b2f(X.a[2]), b2f(X.a[3])} * rrB * kInvSqrt3;
                accvA[0] += f32x2{b2f(V0.a[0]), b2f(V0.a[1])} * m1A;
                accvB[0] += f32x2{b2f(V0.a[2]), b2f(V0.a[3])} * m1B;
                accvA[1] += f32x2{b2f(V1.a[0]), b2f(V1.a[1])} * m1A;
                accvB[1] += f32x2{b2f(V1.a[2]), b2f(V1.a[3])} * m1B;
                accvA[2] += f32x2{b2f(V2.a[0]), b2f(V2.a[1])} * m1A;
                accvB[2] += f32x2{b2f(V2.a[2]), b2f(V2.a[3])} * m1B;
            } else {
                U4 X; X.v = *(const ushort4*)(xhb + (size_t)s * 768 + 512 + c0);
                float4 ev4 = evp[j];
                f32x2 m2A = f32x2{b2f(X.a[0]), b2f(X.a[1])} * rrA;
                f32x2 m2B = f32x2{b2f(X.a[2]), b2f(X.a[3])} * rrB;
                accvA[0] += m2A * ev4.x; accvB[0] += m2B * ev4.x;
                accvA[1] += m2A * ev4.y; accvB[1] += m2B * ev4.y;
                accvA[2] += m2A * ev4.z; accvB[2] += m2B * ev4.z;
            }
        }
        if (p == 0) {
            size_t xi = (size_t)d * 256 + c0;
            float4 xv = *(const float4*)&x[xi];
            xv.x = (xv.x + accxA.x) * kInvSqrt2;
            xv.y = (xv.y + accxA.y) * kInvSqrt2;
            xv.z = (xv.z + accxB.x) * kInvSqrt2;
            xv.w = (xv.w + accxB.y) * kInvSqrt2;
            *(float4*)&x[xi] = xv;
        }
    }
    // epilogue: vecM = vin + dvec * invSqrtH
#pragma unroll
    for (int k = 0; k < 3; ++k) {
        size_t idx = (size_t)d * 768 + k * 256 + c0;
        float4 vv = *(const float4*)&vin[idx];
        vv.x += accvA[k].x * kInvSqrtH;
        vv.y += accvA[k].y * kInvSqrtH;
        vv.z += accvB[k].x * kInvSqrtH;
        vv.w += accvB[k].y * kInvSqrtH;
        *(float4*)&vecM[idx] = vv;
    }
}

// ---------------- vec_dot + hcat(bf16) = [x, vnorm]; vp in bf16 -------------------
__global__ void k_vecdot(const u16* __restrict__ vp, const float* __restrict__ x,
                         float* __restrict__ vec_dot, u16* __restrict__ hcat) {
    int i = blockIdx.x * 256 + threadIdx.x;  // N*H
    int n = i >> 8, c = i & 255;
    const u16* p = vp + (size_t)n * 1536;
    float dsum = 0.f, qsum = 0.f;
#pragma unroll
    for (int k = 0; k < 3; ++k) {
        float v1 = b2f(p[k * 512 + c]);
        float v2 = b2f(p[k * 512 + 256 + c]);
        dsum += v1 * v2;
        qsum += v2 * v2;
    }
    vec_dot[i] = dsum * kInvSqrtH;
    hcat[(size_t)n * 512 + c] = f2b(x[i]);
    hcat[(size_t)n * 512 + 256 + c] = f2b(sqrtf(qsum + 1e-8f));
}

// ---------------- update epilogue + fused LayerNorm for next layer ----------------
__global__ void k_update_out(const u16* __restrict__ hout, const float* __restrict__ vec_dot,
                             const u16* __restrict__ vp, float* __restrict__ x,
                             const float* __restrict__ vecM, float* __restrict__ vfin,
                             u16* __restrict__ vb,
                             const float* __restrict__ lnw, const float* __restrict__ lnb,
                             u16* __restrict__ xout) {
    int n = blockIdx.x, t = threadIdx.x;
    size_t i = (size_t)n * 256 + t;
    float xv1 = b2f(hout[(size_t)n * 768 + t]);
    float xv2 = b2f(hout[(size_t)n * 768 + 256 + t]);
    float xv3 = b2f(hout[(size_t)n * 768 + 512 + t]);
    float dxv = (xv1 + xv2 * vec_dot[i]) * kInvSqrt2;
    float nx = (x[i] + dxv) * kInvSqrt2;
    x[i] = nx;
#pragma unroll
    for (int k = 0; k < 3; ++k) {
        size_t idx = (size_t)n * 768 + k * 256 + t;
        float nv = vecM[idx] + xv3 * b2f(vp[(size_t)n * 1536 + k * 512 + t]);
        vfin[idx] = nv;
        vb[idx] = f2b(nv);
    }
    if (lnw) {
        float s = nx, q = nx * nx;
#pragma unroll
        for (int m = 32; m >= 1; m >>= 1) {
            s += __shfl_xor(s, m, 64);
            q += __shfl_xor(q, m, 64);
        }
        __shared__ float s_sum[4], s_sq[4];
        int wid = t >> 6;
        if ((t & 63) == 0) { s_sum[wid] = s; s_sq[wid] = q; }
        __syncthreads();
        float S = s_sum[0] + s_sum[1] + s_sum[2] + s_sum[3];
        float Q = s_sq[0] + s_sq[1] + s_sq[2] + s_sq[3];
        float mu = S * (1.0f / HH);
        float var = Q * (1.0f / HH) - mu * mu;
        float rs = rsqrtf(var + 1e-5f);
        xout[i] = f2b((nx - mu) * rs * lnw[t] + lnb[t]);
    } else {
        xout[i] = f2b(nx);
    }
}

// ---------------- energy reduce ----------------
__global__ void k_energy2(const float* __restrict__ h, const float* __restrict__ w2,
                          const float* __restrict__ b2, const int* __restrict__ batch,
                          float* __restrict__ out) {
    __shared__ float g[NGG];
    int t = threadIdx.x;
    if (t < NGG) g[t] = 0.f;
    __syncthreads();
    int a = blockIdx.x * 256 + t;
    const float4* hr = (const float4*)(h + (size_t)a * 128);
    const float4* w4 = (const float4*)w2;
    float acc = 0.f;
#pragma unroll 8
    for (int i = 0; i < 32; ++i) {
        float4 hv = hr[i], wv = w4[i];
        acc += hv.x * wv.x + hv.y * wv.y + hv.z * wv.z + hv.w * wv.w;
    }
    acc += b2[0];
    atomicAdd(&g[batch[a]], acc);
    __syncthreads();
    if (t < NGG && g[t] != 0.f) atomicAdd(&out[t], g[t]);
}

extern "C" void kernel_launch(void* const* d_in, const int* in_sizes, int n_in,
                              void* d_out, int out_size, void* d_ws, size_t ws_size,
                              hipStream_t stream) {
    const float* pos      = (const float*)d_in[0];
    const float* atom_emb = (const float*)d_in[1];
    const float* ln_w     = (const float*)d_in[2];
    const float* ln_b     = (const float*)d_in[3];
    const float* xp_w1    = (const float*)d_in[4];
    const float* xp_b1    = (const float*)d_in[5];
    const float* xp_w2    = (const float*)d_in[6];
    const float* xp_b2    = (const float*)d_in[7];
    const float* rbf_w    = (const float*)d_in[8];
    const float* rbf_b    = (const float*)d_in[9];
    const float* vec_w    = (const float*)d_in[10];
    const float* xv_w1    = (const float*)d_in[11];
    const float* xv_b1    = (const float*)d_in[12];
    const float* xv_w2    = (const float*)d_in[13];
    const float* xv_b2    = (const float*)d_in[14];
    const float* oe_w1    = (const float*)d_in[15];
    const float* oe_b1    = (const float*)d_in[16];
    const float* oe_w2    = (const float*)d_in[17];
    const float* oe_b2    = (const float*)d_in[18];
    const int*   z        = (const int*)d_in[19];
    const int*   ei       = (const int*)d_in[20];
    const int*   batch    = (const int*)d_in[21];
    float* out = (float*)d_out;

    char* ws = (char*)d_ws;
    size_t off = 0;
    auto alloc = [&](size_t b) {
        void* p = ws + off;
        off = (off + b + 255) & ~(size_t)255;
        return p;
    };
    float*  x      = (float*)alloc((size_t)NN * HH * 4);       //   8 MB
    float*  vecA   = (float*)alloc((size_t)NN * 768 * 4);      //  24 MB  \ adjacent:
    u16*    vb     = (u16*)alloc((size_t)NN * 768 * 2);        //  12 MB  / joint zero
    float*  vecM   = (float*)alloc((size_t)NN * 768 * 4);      //  24 MB
    u16*    xlnb   = (u16*)alloc((size_t)NN * HH * 2);         //   4 MB (alias xb)
    u16*    t1b    = (u16*)alloc((size_t)NN * HH * 2);         //   4 MB (alias h1b)
    u16*    xhb    = (u16*)alloc((size_t)NN * 768 * 2);        //  12 MB (alias hcatb)
    float*  vdot   = (float*)alloc((size_t)NN * HH * 4);       //   8 MB (alias heng)
    u16*    vpb    = (u16*)alloc((size_t)NN * 1536 * 2);       //  24 MB
    u16*    houtb  = (u16*)alloc((size_t)NN * 768 * 2);        //  12 MB
    float*  ev     = (float*)alloc((size_t)EE * 4 * 4);        //   2 MB
    int*    deg    = (int*)alloc((size_t)NN * 4);
    int*    row_ptr= (int*)alloc((size_t)(NN + 1) * 4);
    int*    fill   = (int*)alloc((size_t)NN * 4);
    int*    dorder = (int*)alloc((size_t)NN * 4);
    int*    srcp   = (int*)alloc((size_t)EE * 4);
    float4* evp    = (float4*)alloc((size_t)EE * 16);          //   2 MB
    int*    k0tab  = (int*)alloc((size_t)EE * 4);              // 0.5 MB
    float*  gtab   = (float*)alloc((size_t)EE * 8 * 4);        //   4 MB
    u16* xp_w1T   = (u16*)alloc((size_t)3 * 256 * 256 * 2);
    u16* xp_w2T   = (u16*)alloc((size_t)3 * 768 * 256 * 2);
    u16* rbf_wP   = (u16*)alloc((size_t)3 * 128 * 768 * 2);    // pair-interleaved bf16
    u16* vec_wT   = (u16*)alloc((size_t)3 * 512 * 256 * 2);
    u16* xv_w1T   = (u16*)alloc((size_t)3 * 256 * 512 * 2);
    u16* xv_w2T   = (u16*)alloc((size_t)3 * 768 * 256 * 2);
    u16* oe_w1T   = (u16*)alloc((size_t)128 * 256 * 2);
    (void)ws_size;

    u16*   h1b   = t1b;
    u16*   hcatb = xhb;
    float* heng  = vdot;
    u16*   xb    = xlnb;

    // ---- setup ----
    k_wt_all<<<2432, 256, 0, stream>>>(xp_w1, xp_w2, rbf_w, vec_w, xv_w1, xv_w2, oe_w1,
                                       xp_w1T, xp_w2T, rbf_wP, vec_wT, xv_w1T, xv_w2T, oe_w1T);
    k_zero<<<(36 * 1024 * 1024 / 16 + 255) / 256, 256, 0, stream>>>(vecA, 36 * 1024 * 1024 / 16);
    k_zero<<<8, 256, 0, stream>>>((float*)deg, NN / 4);
    k_init_ln<<<NN, 256, 0, stream>>>(atom_emb, z, ln_w, ln_b, x, xlnb);
    k_geom_hist<<<EE / 256, 256, 0, stream>>>(pos, ei, ev, deg);
    k_scan_sort<<<1, 256, 0, stream>>>(deg, row_ptr, fill, dorder);
    k_scatter<<<EE / 256, 256, 0, stream>>>(ei, ev, fill, srcp, evp, k0tab, gtab);

    for (int l = 0; l < LL; ++l) {
        // ---- PaiNNMessage ----
        k_gemm<0, 1, 1><<<dim3(2, NN / 128), 256, 0, stream>>>(
            xlnb, xp_w1T + (size_t)l * 256 * 256, xp_b1 + l * HH, t1b, NN, 256, 256);
        k_gemm<0, 1, 0><<<dim3(6, NN / 128), 256, 0, stream>>>(
            t1b, xp_w2T + (size_t)l * 768 * 256, xp_b2 + l * 768, xhb, NN, 256, 768);
        k_msg<<<NN / MSG_WAVES, 1024, 0, stream>>>(
            xhb, vb, srcp, evp, row_ptr, k0tab, gtab,
            rbf_wP + (size_t)l * 128 * 768, rbf_b + l * 768, x, vecA, vecM, dorder);

        // ---- PaiNNUpdate ----
        k_gemm<1, 1, 0><<<dim3(4, 3 * NN / 128), 256, 0, stream>>>(
            vecM, vec_wT + (size_t)l * 512 * 256, nullptr, vpb, 3 * NN, 256, 512);
        k_vecdot<<<NN, 256, 0, stream>>>(vpb, x, vdot, hcatb);
        k_gemm<0, 1, 1><<<dim3(2, NN / 128), 256, 0, stream>>>(
            hcatb, xv_w1T + (size_t)l * 256 * 512, xv_b1 + l * HH, h1b, NN, 512, 256);
        k_gemm<0, 1, 0><<<dim3(6, NN / 128), 256, 0, stream>>>(
            h1b, xv_w2T + (size_t)l * 768 * 256, xv_b2 + l * 768, houtb, NN, 256, 768);
        bool last = (l == LL - 1);
        k_update_out<<<NN, 256, 0, stream>>>(
            houtb, vdot, vpb, x, vecM, vecA, vb,
            last ? nullptr : ln_w + (l + 1) * HH,
            last ? nullptr : ln_b + (l + 1) * HH, xlnb);
    }

    // ---- energy head ----
    k_gemm<0, 0, 1><<<dim3(1, NN / 128), 256, 0, stream>>>(
        xb, oe_w1T, oe_b1, heng, NN, 256, 128);
    k_zero<<<1, 256, 0, stream>>>(out, NGG / 4);
    k_energy2<<<32, 256, 0, stream>>>(heng, oe_w2, oe_b2, batch, out);
}

// Round 16
// 817.904 us; speedup vs baseline: 1.0018x; 1.0018x over previous
//
#include <hip/hip_runtime.h>
#include <hip/hip_bf16.h>
#include <math.h>

#define NN 8192
#define EE 131072
#define HH 256
#define LL 3
#define RR 128
#define NGG 64
#define MSG_WAVES 16         // waves per k_msg block (1024 threads)

typedef __attribute__((ext_vector_type(8))) short bf16x8;
typedef __attribute__((ext_vector_type(4))) float f32x4;
typedef unsigned short u16;

union U4 { ushort4 v; unsigned short a[4]; };
union U8 { uint4 v; unsigned short a[8]; };

__device__ __forceinline__ float silu(float v) { return v / (1.0f + expf(-v)); }
__device__ __forceinline__ float b2f(unsigned short u) { return __uint_as_float(((unsigned)u) << 16); }
__device__ __forceinline__ unsigned short f2b(float f) {
    unsigned u = __float_as_uint(f);
    u += 0x7fff + ((u >> 16) & 1);
    return (unsigned short)(u >> 16);
}

constexpr float kInvSqrt2 = 0.70710678118654752440f;
constexpr float kInvSqrt3 = 0.57735026918962576451f;
constexpr float kInvSqrtH = 0.0625f; // 1/sqrt(256)

// ---------------- utility ----------------
__global__ void k_zero(float* __restrict__ p, int n4) {
    int i = blockIdx.x * 256 + threadIdx.x;
    if (i < n4) ((float4*)p)[i] = make_float4(0.f, 0.f, 0.f, 0.f);
}

// ---------------- ALL weight prep in one launch ----------------
// transpose in[K,N] fp32 -> out[N,K] bf16, except rbf_w: straight cast (k-major kept)
__global__ __launch_bounds__(256) void k_wt_all(
    const float* __restrict__ xp_w1, const float* __restrict__ xp_w2,
    const float* __restrict__ rbf_w, const float* __restrict__ vec_w,
    const float* __restrict__ xv_w1, const float* __restrict__ xv_w2,
    const float* __restrict__ oe_w1,
    u16* __restrict__ xp_w1T, u16* __restrict__ xp_w2T, u16* __restrict__ rbf_wKb,
    u16* __restrict__ vec_wT, u16* __restrict__ xv_w1T, u16* __restrict__ xv_w2T,
    u16* __restrict__ oe_w1T) {
    int bid = blockIdx.x;
    const float* src; u16* dst; int K, N, t, cast = 0;
    if (bid < 2400) {
        int l = bid / 800, r = bid % 800;
        if (r < 64)       { src = xp_w1 + (size_t)l * 65536;  dst = xp_w1T + (size_t)l * 65536;  K = 256; N = 256; t = r; }
        else if (r < 256) { src = xp_w2 + (size_t)l * 196608; dst = xp_w2T + (size_t)l * 196608; K = 256; N = 768; t = r - 64; }
        else if (r < 352) { src = rbf_w + (size_t)l * 98304;  dst = rbf_wKb + (size_t)l * 98304; K = 128; N = 768; t = r - 256; cast = 1; }
        else if (r < 480) { src = vec_w + (size_t)l * 131072; dst = vec_wT + (size_t)l * 131072; K = 256; N = 512; t = r - 352; }
        else if (r < 608) { src = xv_w1 + (size_t)l * 131072; dst = xv_w1T + (size_t)l * 131072; K = 512; N = 256; t = r - 480; }
        else              { src = xv_w2 + (size_t)l * 196608; dst = xv_w2T + (size_t)l * 196608; K = 256; N = 768; t = r - 608; }
    } else {
        src = oe_w1; dst = oe_w1T; K = 256; N = 128; t = bid - 2400;
    }
    int nx = N >> 5;
    int bn = (t % nx) * 32, bk = (t / nx) * 32;
    int tx = threadIdx.x & 31, ty = threadIdx.x >> 5;   // 32 x 8
    if (cast) {
#pragma unroll
        for (int i = 0; i < 32; i += 8)
            dst[(size_t)(bk + ty + i) * N + bn + tx] = f2b(src[(size_t)(bk + ty + i) * N + bn + tx]);
        return;
    }
    __shared__ float tile[32][33];
#pragma unroll
    for (int i = 0; i < 32; i += 8)
        tile[ty + i][tx] = src[(size_t)(bk + ty + i) * N + bn + tx];
    __syncthreads();
#pragma unroll
    for (int i = 0; i < 32; i += 8)
        dst[(size_t)(bn + ty + i) * K + bk + tx] = f2b(tile[tx][ty + i]);
}

// ---------------- init: x = atom_emb[z], + LayerNorm(ln[0]) -> xlnb ----------------
__global__ void k_init_ln(const float* __restrict__ emb, const int* __restrict__ z,
                          const float* __restrict__ w, const float* __restrict__ b,
                          float* __restrict__ x, u16* __restrict__ xlnb) {
    int n = blockIdx.x, t = threadIdx.x;
    float v = emb[z[n] * HH + t];
    x[(size_t)n * HH + t] = v;
    float s = v, q = v * v;
#pragma unroll
    for (int m = 32; m >= 1; m >>= 1) {
        s += __shfl_xor(s, m, 64);
        q += __shfl_xor(q, m, 64);
    }
    __shared__ float s_sum[4], s_sq[4];
    int wid = t >> 6;
    if ((t & 63) == 0) { s_sum[wid] = s; s_sq[wid] = q; }
    __syncthreads();
    float S = s_sum[0] + s_sum[1] + s_sum[2] + s_sum[3];
    float Q = s_sq[0] + s_sq[1] + s_sq[2] + s_sq[3];
    float mu = S * (1.0f / HH);
    float var = Q * (1.0f / HH) - mu * mu;
    float rs = rsqrtf(var + 1e-5f);
    xlnb[(size_t)n * HH + t] = f2b((v - mu) * rs * w[t] + b[t]);
}

// ---------------- edge geometry + degree histogram (fused) ----------------
__global__ void k_geom_hist(const float* __restrict__ pos, const int* __restrict__ ei,
                            float* __restrict__ ev, int* __restrict__ deg) {
    int e = blockIdx.x * 256 + threadIdx.x;
    if (e >= EE) return;
    int s = ei[e], d = ei[EE + e];
    float rx = pos[s * 3 + 0] - pos[d * 3 + 0];
    float ry = pos[s * 3 + 1] - pos[d * 3 + 1];
    float rz = pos[s * 3 + 2] - pos[d * 3 + 2];
    float dist = sqrtf(rx * rx + ry * ry + rz * rz);
    float inv = 1.0f / dist;
    ((float4*)ev)[e] = make_float4(rx * inv, ry * inv, rz * inv, dist);
    atomicAdd(&deg[d], 1);
}

// ---------------- scan (CSR row_ptr) + degree bucket-sort, one block ---------------
__global__ void k_scan_sort(const int* __restrict__ deg, int* __restrict__ row_ptr,
                            int* __restrict__ fill, int* __restrict__ dorder) {
    __shared__ int buf[256];
    __shared__ int carry_s;
    int t = threadIdx.x;
    if (t == 0) carry_s = 0;
    __syncthreads();
    for (int r = 0; r < NN; r += 256) {
        int v = deg[r + t];
        buf[t] = v;
        __syncthreads();
        for (int ofs = 1; ofs < 256; ofs <<= 1) {
            int add = (t >= ofs) ? buf[t - ofs] : 0;
            __syncthreads();
            buf[t] += add;
            __syncthreads();
        }
        int excl = buf[t] - v;
        int carry = carry_s;
        row_ptr[r + t] = carry + excl;
        fill[r + t] = carry + excl;
        __syncthreads();
        if (t == 255) carry_s = carry + buf[t];
        __syncthreads();
    }
    if (t == 0) row_ptr[NN] = carry_s;
    __syncthreads();
    // ---- bucket sort by degree, descending ----
    __shared__ int bins[256];
    __shared__ int base[256];
    bins[t] = 0;
    __syncthreads();
    for (int d = t; d < NN; d += 256) {
        int b = deg[d]; b = b > 255 ? 255 : b;
        atomicAdd(&bins[b], 1);
    }
    __syncthreads();
    if (t == 0) {
        int acc = 0;
        for (int k = 255; k >= 0; --k) { base[k] = acc; acc += bins[k]; }
    }
    __syncthreads();
    bins[t] = 0;
    __syncthreads();
    for (int d = t; d < NN; d += 256) {
        int b = deg[d]; b = b > 255 ? 255 : b;
        int p = atomicAdd(&bins[b], 1);
        dorder[base[b] + p] = d;
    }
}

// scatter + fused per-edge gaussian window table (8 rows, k0 clamp [0,120])
__global__ void k_scatter(const int* __restrict__ ei, const float* __restrict__ ev,
                          int* __restrict__ fill, int* __restrict__ srcp,
                          float4* __restrict__ evp, int* __restrict__ k0tab,
                          float* __restrict__ gtab) {
    int e = blockIdx.x * 256 + threadIdx.x;
    if (e >= EE) return;
    int d = ei[EE + e];
    int pos = atomicAdd(&fill[d], 1);
    float4 e4 = ((const float4*)ev)[e];
    srcp[pos] = ei[e];
    evp[pos] = e4;
    const float step = 12.0f / 127.0f;
    const float coeff = -0.5f / (step * step);
    float dist = e4.w;
    int k0 = (int)floorf(dist / step) - 3;
    k0 = k0 < 0 ? 0 : (k0 > 120 ? 120 : k0);
    float g[8];
#pragma unroll
    for (int k = 0; k < 8; ++k) {
        float t = dist - (k0 + k) * step;
        g[k] = expf(coeff * t * t);
    }
    k0tab[pos] = k0;
    ((float4*)gtab)[pos * 2 + 0] = make_float4(g[0], g[1], g[2], g[3]);
    ((float4*)gtab)[pos * 2 + 1] = make_float4(g[4], g[5], g[6], g[7]);
}

// ---------------- bf16 MFMA GEMM: C = act(A[M,K] @ BT[N,K]^T + bias) ----------------
template <int AF32, int OUT_BF16, int ACT>
__global__ __launch_bounds__(256) void k_gemm(
    const void* __restrict__ Av, const u16* __restrict__ BT,
    const float* __restrict__ bias, void* __restrict__ C, int M, int K, int N) {
    __shared__ uint4 As4[512];
    __shared__ uint4 Bs4[512];
    u16* As = (u16*)As4;
    u16* Bs = (u16*)Bs4;
    int tid = threadIdx.x;
    int wave = tid >> 6, lane = tid & 63;
    int bm = blockIdx.y * 128, bn = blockIdx.x * 128;
    int wm = (wave >> 1) * 64, wn = (wave & 1) * 64;
    int lm = lane & 15;
    int kg = lane >> 4;
    f32x4 acc[4][4] = {};

    for (int k0 = 0; k0 < K; k0 += 32) {
#pragma unroll
        for (int it = 0; it < 2; ++it) {
            int idx = it * 256 + tid;
            int r = idx >> 2, seg = idx & 3;
            if (AF32) {
                const float* Af = (const float*)Av;
                float4 fa = *(const float4*)&Af[(size_t)(bm + r) * K + k0 + seg * 8];
                float4 fb = *(const float4*)&Af[(size_t)(bm + r) * K + k0 + seg * 8 + 4];
                U8 u;
                u.a[0] = f2b(fa.x); u.a[1] = f2b(fa.y); u.a[2] = f2b(fa.z); u.a[3] = f2b(fa.w);
                u.a[4] = f2b(fb.x); u.a[5] = f2b(fb.y); u.a[6] = f2b(fb.z); u.a[7] = f2b(fb.w);
                As4[idx] = u.v;
            } else {
                const u16* A = (const u16*)Av;
                As4[idx] = *(const uint4*)&A[(size_t)(bm + r) * K + k0 + seg * 8];
            }
            Bs4[idx] = *(const uint4*)&BT[(size_t)(bn + r) * K + k0 + seg * 8];
        }
        __syncthreads();
        bf16x8 af[4], bfr[4];
#pragma unroll
        for (int i = 0; i < 4; ++i)
            af[i] = *(const bf16x8*)&As[(wm + i * 16 + lm) * 32 + kg * 8];
#pragma unroll
        for (int j = 0; j < 4; ++j)
            bfr[j] = *(const bf16x8*)&Bs[(wn + j * 16 + lm) * 32 + kg * 8];
#pragma unroll
        for (int i = 0; i < 4; ++i)
#pragma unroll
            for (int j = 0; j < 4; ++j)
                acc[i][j] = __builtin_amdgcn_mfma_f32_16x16x32_bf16(af[i], bfr[j], acc[i][j], 0, 0, 0);
        __syncthreads();
    }

#pragma unroll
    for (int j = 0; j < 4; ++j) {
        int col = bn + wn + j * 16 + lm;
        float bv = bias ? bias[col] : 0.f;
#pragma unroll
        for (int i = 0; i < 4; ++i) {
            int row0 = bm + wm + i * 16 + kg * 4;
#pragma unroll
            for (int r = 0; r < 4; ++r) {
                float v = acc[i][j][r] + bv;
                if (ACT) v = silu(v);
                if (OUT_BF16)
                    ((u16*)C)[(size_t)(row0 + r) * N + col] = f2b(v);
                else
                    ((float*)C)[(size_t)(row0 + r) * N + col] = v;
            }
        }
    }
}

// ---------------- fused message pass v11: R14 inner + band-paired block order ------
// 16-wave 64KB-panel blocks (R13/R14 winner). Block b -> degree band
// (b<256 ? b : 767-b): with 2 blocks/CU resident and round-robin XCD striping,
// CU pair (j, j+256) gets bands (j, 511-j) -> per-CU work sums ~constant.
__global__ __launch_bounds__(1024) void k_msg(
    const u16* __restrict__ xhb, const u16* __restrict__ vinb,
    const int* __restrict__ srcp, const float4* __restrict__ evp,
    const int* __restrict__ row_ptr, const int* __restrict__ k0tab,
    const float* __restrict__ gtab, const u16* __restrict__ WK /*[128][768] bf16*/,
    const float* __restrict__ rbias, float* __restrict__ x,
    const float* __restrict__ vin, float* __restrict__ vecM,
    const int* __restrict__ dorder) {
    __shared__ u16 Wp[128 * 256];   // 64 KB panel
    int tid = threadIdx.x;
    int wave = tid >> 6, lane = tid & 63;
    int c0 = lane * 4;
    int blk = blockIdx.x;
    int band = (blk < 256) ? blk : (767 - blk);      // LPT fold pairing
    int d = dorder[band * MSG_WAVES + wave];
    int E0 = row_ptr[d], E1 = row_ptr[d + 1];
    float accv[3][4] = {};          // persists across panels 1,2

#pragma unroll
    for (int p = 0; p < 3; ++p) {
        __syncthreads();
#pragma unroll
        for (int it = 0; it < 4; ++it) {        // cooperative 64KB panel load
            int idx = it * 1024 + tid;          // 4096 uint4s
            int row = idx >> 5;
            int col8 = (idx & 31) * 8;
            *(uint4*)&Wp[row * 256 + col8] =
                *(const uint4*)&WK[(size_t)row * 768 + p * 256 + col8];
        }
        __syncthreads();
        float4 bb = ((const float4*)(rbias + p * 256))[lane];
        float bias4[4] = {bb.x, bb.y, bb.z, bb.w};
        float accx[4] = {};
        for (int j = E0; j < E1; ++j) {
            int s = srcp[j];
            int kj = k0tab[j];
            float4 ga = ((const float4*)gtab)[(size_t)j * 2 + 0];
            float4 gb = ((const float4*)gtab)[(size_t)j * 2 + 1];
            float g[8] = {ga.x, ga.y, ga.z, ga.w, gb.x, gb.y, gb.z, gb.w};
            float rr[4] = {bias4[0], bias4[1], bias4[2], bias4[3]};
#pragma unroll
            for (int k = 0; k < 8; ++k) {
                U4 w;
                w.v = *(const ushort4*)&Wp[(kj + k) * 256 + c0];
#pragma unroll
                for (int c = 0; c < 4; ++c) rr[c] += g[k] * b2f(w.a[c]);
            }
            if (p == 0) {
                U4 X; X.v = *(const ushort4*)(xhb + (size_t)s * 768 + c0);
#pragma unroll
                for (int c = 0; c < 4; ++c) accx[c] += b2f(X.a[c]) * rr[c];
            } else if (p == 1) {
                U4 X, V0, V1, V2;
                X.v = *(const ushort4*)(xhb + (size_t)s * 768 + 256 + c0);
                V0.v = *(const ushort4*)(vinb + (size_t)s * 768 + c0);
                V1.v = *(const ushort4*)(vinb + (size_t)s * 768 + 256 + c0);
                V2.v = *(const ushort4*)(vinb + (size_t)s * 768 + 512 + c0);
#pragma unroll
                for (int c = 0; c < 4; ++c) {
                    float m1 = b2f(X.a[c]) * rr[c] * kInvSqrt3;
                    accv[0][c] += b2f(V0.a[c]) * m1;
                    accv[1][c] += b2f(V1.a[c]) * m1;
                    accv[2][c] += b2f(V2.a[c]) * m1;
                }
            } else {
                U4 X; X.v = *(const ushort4*)(xhb + (size_t)s * 768 + 512 + c0);
                float4 ev4 = evp[j];
#pragma unroll
                for (int c = 0; c < 4; ++c) {
                    float m2 = b2f(X.a[c]) * rr[c];
                    accv[0][c] += m2 * ev4.x;
                    accv[1][c] += m2 * ev4.y;
                    accv[2][c] += m2 * ev4.z;
                }
            }
        }
        if (p == 0) {
            size_t xi = (size_t)d * 256 + c0;
            float4 xv = *(const float4*)&x[xi];
            xv.x = (xv.x + accx[0]) * kInvSqrt2;
            xv.y = (xv.y + accx[1]) * kInvSqrt2;
            xv.z = (xv.z + accx[2]) * kInvSqrt2;
            xv.w = (xv.w + accx[3]) * kInvSqrt2;
            *(float4*)&x[xi] = xv;
        }
    }
    // epilogue: vecM = vin + dvec * invSqrtH
#pragma unroll
    for (int k = 0; k < 3; ++k) {
        size_t idx = (size_t)d * 768 + k * 256 + c0;
        float4 vv = *(const float4*)&vin[idx];
        vv.x += accv[k][0] * kInvSqrtH;
        vv.y += accv[k][1] * kInvSqrtH;
        vv.z += accv[k][2] * kInvSqrtH;
        vv.w += accv[k][3] * kInvSqrtH;
        *(float4*)&vecM[idx] = vv;
    }
}

// ---------------- vec_dot + hcat(bf16) = [x, vnorm]; vp in bf16 -------------------
__global__ void k_vecdot(const u16* __restrict__ vp, const float* __restrict__ x,
                         float* __restrict__ vec_dot, u16* __restrict__ hcat) {
    int i = blockIdx.x * 256 + threadIdx.x;  // N*H
    int n = i >> 8, c = i & 255;
    const u16* p = vp + (size_t)n * 1536;
    float dsum = 0.f, qsum = 0.f;
#pragma unroll
    for (int k = 0; k < 3; ++k) {
        float v1 = b2f(p[k * 512 + c]);
        float v2 = b2f(p[k * 512 + 256 + c]);
        dsum += v1 * v2;
        qsum += v2 * v2;
    }
    vec_dot[i] = dsum * kInvSqrtH;
    hcat[(size_t)n * 512 + c] = f2b(x[i]);
    hcat[(size_t)n * 512 + 256 + c] = f2b(sqrtf(qsum + 1e-8f));
}

// ---------------- update epilogue + fused LayerNorm for next layer ----------------
__global__ void k_update_out(const u16* __restrict__ hout, const float* __restrict__ vec_dot,
                             const u16* __restrict__ vp, float* __restrict__ x,
                             const float* __restrict__ vecM, float* __restrict__ vfin,
                             u16* __restrict__ vb,
                             const float* __restrict__ lnw, const float* __restrict__ lnb,
                             u16* __restrict__ xout) {
    int n = blockIdx.x, t = threadIdx.x;
    size_t i = (size_t)n * 256 + t;
    float xv1 = b2f(hout[(size_t)n * 768 + t]);
    float xv2 = b2f(hout[(size_t)n * 768 + 256 + t]);
    float xv3 = b2f(hout[(size_t)n * 768 + 512 + t]);
    float dxv = (xv1 + xv2 * vec_dot[i]) * kInvSqrt2;
    float nx = (x[i] + dxv) * kInvSqrt2;
    x[i] = nx;
#pragma unroll
    for (int k = 0; k < 3; ++k) {
        size_t idx = (size_t)n * 768 + k * 256 + t;
        float nv = vecM[idx] + xv3 * b2f(vp[(size_t)n * 1536 + k * 512 + t]);
        vfin[idx] = nv;
        vb[idx] = f2b(nv);
    }
    if (lnw) {
        float s = nx, q = nx * nx;
#pragma unroll
        for (int m = 32; m >= 1; m >>= 1) {
            s += __shfl_xor(s, m, 64);
            q += __shfl_xor(q, m, 64);
        }
        __shared__ float s_sum[4], s_sq[4];
        int wid = t >> 6;
        if ((t & 63) == 0) { s_sum[wid] = s; s_sq[wid] = q; }
        __syncthreads();
        float S = s_sum[0] + s_sum[1] + s_sum[2] + s_sum[3];
        float Q = s_sq[0] + s_sq[1] + s_sq[2] + s_sq[3];
        float mu = S * (1.0f / HH);
        float var = Q * (1.0f / HH) - mu * mu;
        float rs = rsqrtf(var + 1e-5f);
        xout[i] = f2b((nx - mu) * rs * lnw[t] + lnb[t]);
    } else {
        xout[i] = f2b(nx);
    }
}

// ---------------- energy reduce ----------------
__global__ void k_energy2(const float* __restrict__ h, const float* __restrict__ w2,
                          const float* __restrict__ b2, const int* __restrict__ batch,
                          float* __restrict__ out) {
    __shared__ float g[NGG];
    int t = threadIdx.x;
    if (t < NGG) g[t] = 0.f;
    __syncthreads();
    int a = blockIdx.x * 256 + t;
    const float4* hr = (const float4*)(h + (size_t)a * 128);
    const float4* w4 = (const float4*)w2;
    float acc = 0.f;
#pragma unroll 8
    for (int i = 0; i < 32; ++i) {
        float4 hv = hr[i], wv = w4[i];
        acc += hv.x * wv.x + hv.y * wv.y + hv.z * wv.z + hv.w * wv.w;
    }
    acc += b2[0];
    atomicAdd(&g[batch[a]], acc);
    __syncthreads();
    if (t < NGG && g[t] != 0.f) atomicAdd(&out[t], g[t]);
}

extern "C" void kernel_launch(void* const* d_in, const int* in_sizes, int n_in,
                              void* d_out, int out_size, void* d_ws, size_t ws_size,
                              hipStream_t stream) {
    const float* pos      = (const float*)d_in[0];
    const float* atom_emb = (const float*)d_in[1];
    const float* ln_w     = (const float*)d_in[2];
    const float* ln_b     = (const float*)d_in[3];
    const float* xp_w1    = (const float*)d_in[4];
    const float* xp_b1    = (const float*)d_in[5];
    const float* xp_w2    = (const float*)d_in[6];
    const float* xp_b2    = (const float*)d_in[7];
    const float* rbf_w    = (const float*)d_in[8];
    const float* rbf_b    = (const float*)d_in[9];
    const float* vec_w    = (const float*)d_in[10];
    const float* xv_w1    = (const float*)d_in[11];
    const float* xv_b1    = (const float*)d_in[12];
    const float* xv_w2    = (const float*)d_in[13];
    const float* xv_b2    = (const float*)d_in[14];
    const float* oe_w1    = (const float*)d_in[15];
    const float* oe_b1    = (const float*)d_in[16];
    const float* oe_w2    = (const float*)d_in[17];
    const float* oe_b2    = (const float*)d_in[18];
    const int*   z        = (const int*)d_in[19];
    const int*   ei       = (const int*)d_in[20];
    const int*   batch    = (const int*)d_in[21];
    float* out = (float*)d_out;

    char* ws = (char*)d_ws;
    size_t off = 0;
    auto alloc = [&](size_t b) {
        void* p = ws + off;
        off = (off + b + 255) & ~(size_t)255;
        return p;
    };
    float*  x      = (float*)alloc((size_t)NN * HH * 4);       //   8 MB
    float*  vecA   = (float*)alloc((size_t)NN * 768 * 4);      //  24 MB  \ adjacent:
    u16*    vb     = (u16*)alloc((size_t)NN * 768 * 2);        //  12 MB  / joint zero
    float*  vecM   = (float*)alloc((size_t)NN * 768 * 4);      //  24 MB
    u16*    xlnb   = (u16*)alloc((size_t)NN * HH * 2);         //   4 MB (alias xb)
    u16*    t1b    = (u16*)alloc((size_t)NN * HH * 2);         //   4 MB (alias h1b)
    u16*    xhb    = (u16*)alloc((size_t)NN * 768 * 2);        //  12 MB (alias hcatb)
    float*  vdot   = (float*)alloc((size_t)NN * HH * 4);       //   8 MB (alias heng)
    u16*    vpb    = (u16*)alloc((size_t)NN * 1536 * 2);       //  24 MB
    u16*    houtb  = (u16*)alloc((size_t)NN * 768 * 2);        //  12 MB
    float*  ev     = (float*)alloc((size_t)EE * 4 * 4);        //   2 MB
    int*    deg    = (int*)alloc((size_t)NN * 4);
    int*    row_ptr= (int*)alloc((size_t)(NN + 1) * 4);
    int*    fill   = (int*)alloc((size_t)NN * 4);
    int*    dorder = (int*)alloc((size_t)NN * 4);
    int*    srcp   = (int*)alloc((size_t)EE * 4);
    float4* evp    = (float4*)alloc((size_t)EE * 16);          //   2 MB
    int*    k0tab  = (int*)alloc((size_t)EE * 4);              // 0.5 MB
    float*  gtab   = (float*)alloc((size_t)EE * 8 * 4);        //   4 MB
    u16* xp_w1T   = (u16*)alloc((size_t)3 * 256 * 256 * 2);
    u16* xp_w2T   = (u16*)alloc((size_t)3 * 768 * 256 * 2);
    u16* rbf_wKb  = (u16*)alloc((size_t)3 * 128 * 768 * 2);    // k-major bf16 cast
    u16* vec_wT   = (u16*)alloc((size_t)3 * 512 * 256 * 2);
    u16* xv_w1T   = (u16*)alloc((size_t)3 * 256 * 512 * 2);
    u16* xv_w2T   = (u16*)alloc((size_t)3 * 768 * 256 * 2);
    u16* oe_w1T   = (u16*)alloc((size_t)128 * 256 * 2);
    (void)ws_size;

    u16*   h1b   = t1b;
    u16*   hcatb = xhb;
    float* heng  = vdot;
    u16*   xb    = xlnb;

    // ---- setup ----
    k_wt_all<<<2432, 256, 0, stream>>>(xp_w1, xp_w2, rbf_w, vec_w, xv_w1, xv_w2, oe_w1,
                                       xp_w1T, xp_w2T, rbf_wKb, vec_wT, xv_w1T, xv_w2T, oe_w1T);
    k_zero<<<(36 * 1024 * 1024 / 16 + 255) / 256, 256, 0, stream>>>(vecA, 36 * 1024 * 1024 / 16);
    k_zero<<<8, 256, 0, stream>>>((float*)deg, NN / 4);
    k_init_ln<<<NN, 256, 0, stream>>>(atom_emb, z, ln_w, ln_b, x, xlnb);
    k_geom_hist<<<EE / 256, 256, 0, stream>>>(pos, ei, ev, deg);
    k_scan_sort<<<1, 256, 0, stream>>>(deg, row_ptr, fill, dorder);
    k_scatter<<<EE / 256, 256, 0, stream>>>(ei, ev, fill, srcp, evp, k0tab, gtab);

    for (int l = 0; l < LL; ++l) {
        // ---- PaiNNMessage ----
        k_gemm<0, 1, 1><<<dim3(2, NN / 128), 256, 0, stream>>>(
            xlnb, xp_w1T + (size_t)l * 256 * 256, xp_b1 + l * HH, t1b, NN, 256, 256);
        k_gemm<0, 1, 0><<<dim3(6, NN / 128), 256, 0, stream>>>(
            t1b, xp_w2T + (size_t)l * 768 * 256, xp_b2 + l * 768, xhb, NN, 256, 768);
        k_msg<<<NN / MSG_WAVES, 1024, 0, stream>>>(
            xhb, vb, srcp, evp, row_ptr, k0tab, gtab,
            rbf_wKb + (size_t)l * 128 * 768, rbf_b + l * 768, x, vecA, vecM, dorder);

        // ---- PaiNNUpdate ----
        k_gemm<1, 1, 0><<<dim3(4, 3 * NN / 128), 256, 0, stream>>>(
            vecM, vec_wT + (size_t)l * 512 * 256, nullptr, vpb, 3 * NN, 256, 512);
        k_vecdot<<<NN, 256, 0, stream>>>(vpb, x, vdot, hcatb);
        k_gemm<0, 1, 1><<<dim3(2, NN / 128), 256, 0, stream>>>(
            hcatb, xv_w1T + (size_t)l * 256 * 512, xv_b1 + l * HH, h1b, NN, 512, 256);
        k_gemm<0, 1, 0><<<dim3(6, NN / 128), 256, 0, stream>>>(
            h1b, xv_w2T + (size_t)l * 768 * 256, xv_b2 + l * 768, houtb, NN, 256, 768);
        bool last = (l == LL - 1);
        k_update_out<<<NN, 256, 0, stream>>>(
            houtb, vdot, vpb, x, vecM, vecA, vb,
            last ? nullptr : ln_w + (l + 1) * HH,
            last ? nullptr : ln_b + (l + 1) * HH, xlnb);
    }

    // ---- energy head ----
    k_gemm<0, 0, 1><<<dim3(1, NN / 128), 256, 0, stream>>>(
        xb, oe_w1T, oe_b1, heng, NN, 256, 128);
    k_zero<<<1, 256, 0, stream>>>(out, NGG / 4);
    k_energy2<<<32, 256, 0, stream>>>(heng, oe_w2, oe_b2, batch, out);
}

// Round 17
// 802.668 us; speedup vs baseline: 1.0209x; 1.0190x over previous
//
#include <hip/hip_runtime.h>
#include <hip/hip_bf16.h>
#include <math.h>

#define NN 8192
#define EE 131072
#define HH 256
#define LL 3
#define RR 128
#define NGG 64
#define MSG_WAVES 16         // waves per k_msg block (1024 threads)

typedef __attribute__((ext_vector_type(8))) short bf16x8;
typedef __attribute__((ext_vector_type(4))) float f32x4;
typedef unsigned short u16;

#if defined(__has_builtin)
#if __has_builtin(__builtin_amdgcn_fdot2_f32_bf16)
#define HAVE_FDOT2 1
typedef __attribute__((ext_vector_type(2))) __bf16 bf16x2_t;
union BU { unsigned u; bf16x2_t v; };
#endif
#endif

union U4 { ushort4 v; unsigned short a[4]; };
union U8 { uint4 v; unsigned short a[8]; unsigned w[4]; };

__device__ __forceinline__ float silu(float v) { return v / (1.0f + expf(-v)); }
__device__ __forceinline__ float b2f(unsigned short u) { return __uint_as_float(((unsigned)u) << 16); }
__device__ __forceinline__ unsigned short f2b(float f) {
    unsigned u = __float_as_uint(f);
    u += 0x7fff + ((u >> 16) & 1);
    return (unsigned short)(u >> 16);
}

constexpr float kInvSqrt2 = 0.70710678118654752440f;
constexpr float kInvSqrt3 = 0.57735026918962576451f;
constexpr float kInvSqrtH = 0.0625f; // 1/sqrt(256)

// ---------------- utility ----------------
__global__ void k_zero(float* __restrict__ p, int n4) {
    int i = blockIdx.x * 256 + threadIdx.x;
    if (i < n4) ((float4*)p)[i] = make_float4(0.f, 0.f, 0.f, 0.f);
}

// ---------------- ALL weight prep in one launch ----------------
// transpose in[K,N] fp32 -> out[N,K] bf16; rbf_w: row-PAIR interleaved k-major bf16
// rbf layout: dst[(k>>1)*1536 + n*2 + (k&1)]
__global__ __launch_bounds__(256) void k_wt_all(
    const float* __restrict__ xp_w1, const float* __restrict__ xp_w2,
    const float* __restrict__ rbf_w, const float* __restrict__ vec_w,
    const float* __restrict__ xv_w1, const float* __restrict__ xv_w2,
    const float* __restrict__ oe_w1,
    u16* __restrict__ xp_w1T, u16* __restrict__ xp_w2T, u16* __restrict__ rbf_wP,
    u16* __restrict__ vec_wT, u16* __restrict__ xv_w1T, u16* __restrict__ xv_w2T,
    u16* __restrict__ oe_w1T) {
    int bid = blockIdx.x;
    const float* src; u16* dst; int K, N, t, pairmode = 0;
    if (bid < 2400) {
        int l = bid / 800, r = bid % 800;
        if (r < 64)       { src = xp_w1 + (size_t)l * 65536;  dst = xp_w1T + (size_t)l * 65536;  K = 256; N = 256; t = r; }
        else if (r < 256) { src = xp_w2 + (size_t)l * 196608; dst = xp_w2T + (size_t)l * 196608; K = 256; N = 768; t = r - 64; }
        else if (r < 352) { src = rbf_w + (size_t)l * 98304;  dst = rbf_wP + (size_t)l * 98304;  K = 128; N = 768; t = r - 256; pairmode = 1; }
        else if (r < 480) { src = vec_w + (size_t)l * 131072; dst = vec_wT + (size_t)l * 131072; K = 256; N = 512; t = r - 352; }
        else if (r < 608) { src = xv_w1 + (size_t)l * 131072; dst = xv_w1T + (size_t)l * 131072; K = 512; N = 256; t = r - 480; }
        else              { src = xv_w2 + (size_t)l * 196608; dst = xv_w2T + (size_t)l * 196608; K = 256; N = 768; t = r - 608; }
    } else {
        src = oe_w1; dst = oe_w1T; K = 256; N = 128; t = bid - 2400;
    }
    int nx = N >> 5;
    int bn = (t % nx) * 32, bk = (t / nx) * 32;
    int tx = threadIdx.x & 31, ty = threadIdx.x >> 5;   // 32 x 8
    if (pairmode) {
#pragma unroll
        for (int i = 0; i < 32; i += 8) {
            int k = bk + ty + i, n = bn + tx;
            dst[(size_t)(k >> 1) * 1536 + n * 2 + (k & 1)] = f2b(src[(size_t)k * N + n]);
        }
        return;
    }
    __shared__ float tile[32][33];
#pragma unroll
    for (int i = 0; i < 32; i += 8)
        tile[ty + i][tx] = src[(size_t)(bk + ty + i) * N + bn + tx];
    __syncthreads();
#pragma unroll
    for (int i = 0; i < 32; i += 8)
        dst[(size_t)(bn + ty + i) * K + bk + tx] = f2b(tile[tx][ty + i]);
}

// ---------------- init: x = atom_emb[z], + LayerNorm(ln[0]) -> xlnb ----------------
__global__ void k_init_ln(const float* __restrict__ emb, const int* __restrict__ z,
                          const float* __restrict__ w, const float* __restrict__ b,
                          float* __restrict__ x, u16* __restrict__ xlnb) {
    int n = blockIdx.x, t = threadIdx.x;
    float v = emb[z[n] * HH + t];
    x[(size_t)n * HH + t] = v;
    float s = v, q = v * v;
#pragma unroll
    for (int m = 32; m >= 1; m >>= 1) {
        s += __shfl_xor(s, m, 64);
        q += __shfl_xor(q, m, 64);
    }
    __shared__ float s_sum[4], s_sq[4];
    int wid = t >> 6;
    if ((t & 63) == 0) { s_sum[wid] = s; s_sq[wid] = q; }
    __syncthreads();
    float S = s_sum[0] + s_sum[1] + s_sum[2] + s_sum[3];
    float Q = s_sq[0] + s_sq[1] + s_sq[2] + s_sq[3];
    float mu = S * (1.0f / HH);
    float var = Q * (1.0f / HH) - mu * mu;
    float rs = rsqrtf(var + 1e-5f);
    xlnb[(size_t)n * HH + t] = f2b((v - mu) * rs * w[t] + b[t]);
}

// ---------------- edge geometry + degree histogram (fused) ----------------
__global__ void k_geom_hist(const float* __restrict__ pos, const int* __restrict__ ei,
                            float* __restrict__ ev, int* __restrict__ deg) {
    int e = blockIdx.x * 256 + threadIdx.x;
    if (e >= EE) return;
    int s = ei[e], d = ei[EE + e];
    float rx = pos[s * 3 + 0] - pos[d * 3 + 0];
    float ry = pos[s * 3 + 1] - pos[d * 3 + 1];
    float rz = pos[s * 3 + 2] - pos[d * 3 + 2];
    float dist = sqrtf(rx * rx + ry * ry + rz * rz);
    float inv = 1.0f / dist;
    ((float4*)ev)[e] = make_float4(rx * inv, ry * inv, rz * inv, dist);
    atomicAdd(&deg[d], 1);
}

// ---------------- scan (CSR row_ptr) + degree bucket-sort, one block ---------------
__global__ void k_scan_sort(const int* __restrict__ deg, int* __restrict__ row_ptr,
                            int* __restrict__ fill, int* __restrict__ dorder) {
    __shared__ int buf[256];
    __shared__ int carry_s;
    int t = threadIdx.x;
    if (t == 0) carry_s = 0;
    __syncthreads();
    for (int r = 0; r < NN; r += 256) {
        int v = deg[r + t];
        buf[t] = v;
        __syncthreads();
        for (int ofs = 1; ofs < 256; ofs <<= 1) {
            int add = (t >= ofs) ? buf[t - ofs] : 0;
            __syncthreads();
            buf[t] += add;
            __syncthreads();
        }
        int excl = buf[t] - v;
        int carry = carry_s;
        row_ptr[r + t] = carry + excl;
        fill[r + t] = carry + excl;
        __syncthreads();
        if (t == 255) carry_s = carry + buf[t];
        __syncthreads();
    }
    if (t == 0) row_ptr[NN] = carry_s;
    __syncthreads();
    __shared__ int bins[256];
    __shared__ int base[256];
    bins[t] = 0;
    __syncthreads();
    for (int d = t; d < NN; d += 256) {
        int b = deg[d]; b = b > 255 ? 255 : b;
        atomicAdd(&bins[b], 1);
    }
    __syncthreads();
    if (t == 0) {
        int acc = 0;
        for (int k = 255; k >= 0; --k) { base[k] = acc; acc += bins[k]; }
    }
    __syncthreads();
    bins[t] = 0;
    __syncthreads();
    for (int d = t; d < NN; d += 256) {
        int b = deg[d]; b = b > 255 ? 255 : b;
        int p = atomicAdd(&bins[b], 1);
        dorder[base[b] + p] = d;
    }
}

// scatter + gaussian window: 8 rows, EVEN-aligned k0; gtab packed bf16 pairs (16B)
__global__ void k_scatter(const int* __restrict__ ei, const float* __restrict__ ev,
                          int* __restrict__ fill, int* __restrict__ srcp,
                          float4* __restrict__ evp, int* __restrict__ kptab,
                          unsigned* __restrict__ gtab) {
    int e = blockIdx.x * 256 + threadIdx.x;
    if (e >= EE) return;
    int d = ei[EE + e];
    int pos = atomicAdd(&fill[d], 1);
    float4 e4 = ((const float4*)ev)[e];
    srcp[pos] = ei[e];
    evp[pos] = e4;
    const float step = 12.0f / 127.0f;
    const float coeff = -0.5f / (step * step);
    float dist = e4.w;
    int k0 = ((int)floorf(dist / step) - 3) & ~1;   // even-aligned
    k0 = k0 < 0 ? 0 : (k0 > 120 ? 120 : k0);
    float g[8];
#pragma unroll
    for (int k = 0; k < 8; ++k) {
        float t = dist - (k0 + k) * step;
        g[k] = expf(coeff * t * t);
    }
    kptab[pos] = k0 >> 1;
    unsigned g0 = (unsigned)f2b(g[0]) | ((unsigned)f2b(g[1]) << 16);
    unsigned g1 = (unsigned)f2b(g[2]) | ((unsigned)f2b(g[3]) << 16);
    unsigned g2 = (unsigned)f2b(g[4]) | ((unsigned)f2b(g[5]) << 16);
    unsigned g3 = (unsigned)f2b(g[6]) | ((unsigned)f2b(g[7]) << 16);
    ((uint4*)gtab)[pos] = make_uint4(g0, g1, g2, g3);
}

// ---------------- bf16 MFMA GEMM: C = act(A[M,K] @ BT[N,K]^T + bias) ----------------
template <int AF32, int OUT_BF16, int ACT>
__global__ __launch_bounds__(256) void k_gemm(
    const void* __restrict__ Av, const u16* __restrict__ BT,
    const float* __restrict__ bias, void* __restrict__ C, int M, int K, int N) {
    __shared__ uint4 As4[512];
    __shared__ uint4 Bs4[512];
    u16* As = (u16*)As4;
    u16* Bs = (u16*)Bs4;
    int tid = threadIdx.x;
    int wave = tid >> 6, lane = tid & 63;
    int bm = blockIdx.y * 128, bn = blockIdx.x * 128;
    int wm = (wave >> 1) * 64, wn = (wave & 1) * 64;
    int lm = lane & 15;
    int kg = lane >> 4;
    f32x4 acc[4][4] = {};

    for (int k0 = 0; k0 < K; k0 += 32) {
#pragma unroll
        for (int it = 0; it < 2; ++it) {
            int idx = it * 256 + tid;
            int r = idx >> 2, seg = idx & 3;
            if (AF32) {
                const float* Af = (const float*)Av;
                float4 fa = *(const float4*)&Af[(size_t)(bm + r) * K + k0 + seg * 8];
                float4 fb = *(const float4*)&Af[(size_t)(bm + r) * K + k0 + seg * 8 + 4];
                U8 u;
                u.a[0] = f2b(fa.x); u.a[1] = f2b(fa.y); u.a[2] = f2b(fa.z); u.a[3] = f2b(fa.w);
                u.a[4] = f2b(fb.x); u.a[5] = f2b(fb.y); u.a[6] = f2b(fb.z); u.a[7] = f2b(fb.w);
                As4[idx] = u.v;
            } else {
                const u16* A = (const u16*)Av;
                As4[idx] = *(const uint4*)&A[(size_t)(bm + r) * K + k0 + seg * 8];
            }
            Bs4[idx] = *(const uint4*)&BT[(size_t)(bn + r) * K + k0 + seg * 8];
        }
        __syncthreads();
        bf16x8 af[4], bfr[4];
#pragma unroll
        for (int i = 0; i < 4; ++i)
            af[i] = *(const bf16x8*)&As[(wm + i * 16 + lm) * 32 + kg * 8];
#pragma unroll
        for (int j = 0; j < 4; ++j)
            bfr[j] = *(const bf16x8*)&Bs[(wn + j * 16 + lm) * 32 + kg * 8];
#pragma unroll
        for (int i = 0; i < 4; ++i)
#pragma unroll
            for (int j = 0; j < 4; ++j)
                acc[i][j] = __builtin_amdgcn_mfma_f32_16x16x32_bf16(af[i], bfr[j], acc[i][j], 0, 0, 0);
        __syncthreads();
    }

#pragma unroll
    for (int j = 0; j < 4; ++j) {
        int col = bn + wn + j * 16 + lm;
        float bv = bias ? bias[col] : 0.f;
#pragma unroll
        for (int i = 0; i < 4; ++i) {
            int row0 = bm + wm + i * 16 + kg * 4;
#pragma unroll
            for (int r = 0; r < 4; ++r) {
                float v = acc[i][j][r] + bv;
                if (ACT) v = silu(v);
                if (OUT_BF16)
                    ((u16*)C)[(size_t)(row0 + r) * N + col] = f2b(v);
                else
                    ((float*)C)[(size_t)(row0 + r) * N + col] = v;
            }
        }
    }
}

// ---------------- fused message pass v12: pair-panel + v_dot2_f32_bf16 combine -----
// 16-wave 64KB-panel blocks, degree-sorted dsts (R14 winner). W pair-interleaved:
// each uint4 LDS read = 4 (col, k-pair) bf16x2 operands; rr[c] updated by one fdot2.
__global__ __launch_bounds__(1024) void k_msg(
    const u16* __restrict__ xhb, const u16* __restrict__ vinb,
    const int* __restrict__ srcp, const float4* __restrict__ evp,
    const int* __restrict__ row_ptr, const int* __restrict__ kptab,
    const unsigned* __restrict__ gtab, const u16* __restrict__ WP /*pair-interleaved*/,
    const float* __restrict__ rbias, float* __restrict__ x,
    const float* __restrict__ vin, float* __restrict__ vecM,
    const int* __restrict__ dorder) {
    __shared__ u16 Wp[64 * 512];    // 64 KB: [64 row-pairs][256 cols][2]
    int tid = threadIdx.x;
    int wave = tid >> 6, lane = tid & 63;
    int c0 = lane * 4;
    int d = dorder[blockIdx.x * MSG_WAVES + wave];
    int E0 = row_ptr[d], E1 = row_ptr[d + 1];
    float accv[3][4] = {};          // persists across panels 1,2

#pragma unroll
    for (int p = 0; p < 3; ++p) {
        __syncthreads();
#pragma unroll
        for (int it = 0; it < 4; ++it) {        // cooperative 64KB panel load
            int idx = it * 1024 + tid;          // 4096 uint4
            int r = idx >> 6;                   // 64 row-pairs, 64 uint4/pair
            int c8 = (idx & 63) * 8;
            *(uint4*)&Wp[r * 512 + c8] =
                *(const uint4*)&WP[(size_t)r * 1536 + p * 512 + c8];
        }
        __syncthreads();
        float4 bb = ((const float4*)(rbias + p * 256))[lane];
        float bias4[4] = {bb.x, bb.y, bb.z, bb.w};
        float accx[4] = {};
        for (int j = E0; j < E1; ++j) {
            int s = srcp[j];
            int kp = kptab[j];
            uint4 gt = ((const uint4*)gtab)[j];
            unsigned gp[4] = {gt.x, gt.y, gt.z, gt.w};
            float rr[4] = {bias4[0], bias4[1], bias4[2], bias4[3]};
#pragma unroll
            for (int p2 = 0; p2 < 4; ++p2) {
                U8 w;
                w.v = *(const uint4*)&Wp[(kp + p2) * 512 + c0 * 2];  // ds_read_b128
#ifdef HAVE_FDOT2
                BU gv; gv.u = gp[p2];
#pragma unroll
                for (int c = 0; c < 4; ++c) {
                    BU wv; wv.u = w.w[c];
                    rr[c] = __builtin_amdgcn_fdot2_f32_bf16(wv.v, gv.v, rr[c], false);
                }
#else
                float ge = b2f((u16)(gp[p2] & 0xffff));
                float go = b2f((u16)(gp[p2] >> 16));
#pragma unroll
                for (int c = 0; c < 4; ++c)
                    rr[c] += ge * b2f(w.a[2 * c]) + go * b2f(w.a[2 * c + 1]);
#endif
            }
            if (p == 0) {
                U4 X; X.v = *(const ushort4*)(xhb + (size_t)s * 768 + c0);
#pragma unroll
                for (int c = 0; c < 4; ++c) accx[c] += b2f(X.a[c]) * rr[c];
            } else if (p == 1) {
                U4 X, V0, V1, V2;
                X.v = *(const ushort4*)(xhb + (size_t)s * 768 + 256 + c0);
                V0.v = *(const ushort4*)(vinb + (size_t)s * 768 + c0);
                V1.v = *(const ushort4*)(vinb + (size_t)s * 768 + 256 + c0);
                V2.v = *(const ushort4*)(vinb + (size_t)s * 768 + 512 + c0);
#pragma unroll
                for (int c = 0; c < 4; ++c) {
                    float m1 = b2f(X.a[c]) * rr[c] * kInvSqrt3;
                    accv[0][c] += b2f(V0.a[c]) * m1;
                    accv[1][c] += b2f(V1.a[c]) * m1;
                    accv[2][c] += b2f(V2.a[c]) * m1;
                }
            } else {
                U4 X; X.v = *(const ushort4*)(xhb + (size_t)s * 768 + 512 + c0);
                float4 ev4 = evp[j];
#pragma unroll
                for (int c = 0; c < 4; ++c) {
                    float m2 = b2f(X.a[c]) * rr[c];
                    accv[0][c] += m2 * ev4.x;
                    accv[1][c] += m2 * ev4.y;
                    accv[2][c] += m2 * ev4.z;
                }
            }
        }
        if (p == 0) {
            size_t xi = (size_t)d * 256 + c0;
            float4 xv = *(const float4*)&x[xi];
            xv.x = (xv.x + accx[0]) * kInvSqrt2;
            xv.y = (xv.y + accx[1]) * kInvSqrt2;
            xv.z = (xv.z + accx[2]) * kInvSqrt2;
            xv.w = (xv.w + accx[3]) * kInvSqrt2;
            *(float4*)&x[xi] = xv;
        }
    }
    // epilogue: vecM = vin + dvec * invSqrtH
#pragma unroll
    for (int k = 0; k < 3; ++k) {
        size_t idx = (size_t)d * 768 + k * 256 + c0;
        float4 vv = *(const float4*)&vin[idx];
        vv.x += accv[k][0] * kInvSqrtH;
        vv.y += accv[k][1] * kInvSqrtH;
        vv.z += accv[k][2] * kInvSqrtH;
        vv.w += accv[k][3] * kInvSqrtH;
        *(float4*)&vecM[idx] = vv;
    }
}

// ---------------- vec_dot + hcat(bf16) = [x, vnorm]; vp in bf16 -------------------
__global__ void k_vecdot(const u16* __restrict__ vp, const float* __restrict__ x,
                         float* __restrict__ vec_dot, u16* __restrict__ hcat) {
    int i = blockIdx.x * 256 + threadIdx.x;  // N*H
    int n = i >> 8, c = i & 255;
    const u16* p = vp + (size_t)n * 1536;
    float dsum = 0.f, qsum = 0.f;
#pragma unroll
    for (int k = 0; k < 3; ++k) {
        float v1 = b2f(p[k * 512 + c]);
        float v2 = b2f(p[k * 512 + 256 + c]);
        dsum += v1 * v2;
        qsum += v2 * v2;
    }
    vec_dot[i] = dsum * kInvSqrtH;
    hcat[(size_t)n * 512 + c] = f2b(x[i]);
    hcat[(size_t)n * 512 + 256 + c] = f2b(sqrtf(qsum + 1e-8f));
}

// ---------------- update epilogue + fused LayerNorm for next layer ----------------
__global__ void k_update_out(const u16* __restrict__ hout, const float* __restrict__ vec_dot,
                             const u16* __restrict__ vp, float* __restrict__ x,
                             const float* __restrict__ vecM, float* __restrict__ vfin,
                             u16* __restrict__ vb,
                             const float* __restrict__ lnw, const float* __restrict__ lnb,
                             u16* __restrict__ xout) {
    int n = blockIdx.x, t = threadIdx.x;
    size_t i = (size_t)n * 256 + t;
    float xv1 = b2f(hout[(size_t)n * 768 + t]);
    float xv2 = b2f(hout[(size_t)n * 768 + 256 + t]);
    float xv3 = b2f(hout[(size_t)n * 768 + 512 + t]);
    float dxv = (xv1 + xv2 * vec_dot[i]) * kInvSqrt2;
    float nx = (x[i] + dxv) * kInvSqrt2;
    x[i] = nx;
#pragma unroll
    for (int k = 0; k < 3; ++k) {
        size_t idx = (size_t)n * 768 + k * 256 + t;
        float nv = vecM[idx] + xv3 * b2f(vp[(size_t)n * 1536 + k * 512 + t]);
        vfin[idx] = nv;
        vb[idx] = f2b(nv);
    }
    if (lnw) {
        float s = nx, q = nx * nx;
#pragma unroll
        for (int m = 32; m >= 1; m >>= 1) {
            s += __shfl_xor(s, m, 64);
            q += __shfl_xor(q, m, 64);
        }
        __shared__ float s_sum[4], s_sq[4];
        int wid = t >> 6;
        if ((t & 63) == 0) { s_sum[wid] = s; s_sq[wid] = q; }
        __syncthreads();
        float S = s_sum[0] + s_sum[1] + s_sum[2] + s_sum[3];
        float Q = s_sq[0] + s_sq[1] + s_sq[2] + s_sq[3];
        float mu = S * (1.0f / HH);
        float var = Q * (1.0f / HH) - mu * mu;
        float rs = rsqrtf(var + 1e-5f);
        xout[i] = f2b((nx - mu) * rs * lnw[t] + lnb[t]);
    } else {
        xout[i] = f2b(nx);
    }
}

// ---------------- energy reduce ----------------
__global__ void k_energy2(const float* __restrict__ h, const float* __restrict__ w2,
                          const float* __restrict__ b2, const int* __restrict__ batch,
                          float* __restrict__ out) {
    __shared__ float g[NGG];
    int t = threadIdx.x;
    if (t < NGG) g[t] = 0.f;
    __syncthreads();
    int a = blockIdx.x * 256 + t;
    const float4* hr = (const float4*)(h + (size_t)a * 128);
    const float4* w4 = (const float4*)w2;
    float acc = 0.f;
#pragma unroll 8
    for (int i = 0; i < 32; ++i) {
        float4 hv = hr[i], wv = w4[i];
        acc += hv.x * wv.x + hv.y * wv.y + hv.z * wv.z + hv.w * wv.w;
    }
    acc += b2[0];
    atomicAdd(&g[batch[a]], acc);
    __syncthreads();
    if (t < NGG && g[t] != 0.f) atomicAdd(&out[t], g[t]);
}

extern "C" void kernel_launch(void* const* d_in, const int* in_sizes, int n_in,
                              void* d_out, int out_size, void* d_ws, size_t ws_size,
                              hipStream_t stream) {
    const float* pos      = (const float*)d_in[0];
    const float* atom_emb = (const float*)d_in[1];
    const float* ln_w     = (const float*)d_in[2];
    const float* ln_b     = (const float*)d_in[3];
    const float* xp_w1    = (const float*)d_in[4];
    const float* xp_b1    = (const float*)d_in[5];
    const float* xp_w2    = (const float*)d_in[6];
    const float* xp_b2    = (const float*)d_in[7];
    const float* rbf_w    = (const float*)d_in[8];
    const float* rbf_b    = (const float*)d_in[9];
    const float* vec_w    = (const float*)d_in[10];
    const float* xv_w1    = (const float*)d_in[11];
    const float* xv_b1    = (const float*)d_in[12];
    const float* xv_w2    = (const float*)d_in[13];
    const float* xv_b2    = (const float*)d_in[14];
    const float* oe_w1    = (const float*)d_in[15];
    const float* oe_b1    = (const float*)d_in[16];
    const float* oe_w2    = (const float*)d_in[17];
    const float* oe_b2    = (const float*)d_in[18];
    const int*   z        = (const int*)d_in[19];
    const int*   ei       = (const int*)d_in[20];
    const int*   batch    = (const int*)d_in[21];
    float* out = (float*)d_out;

    char* ws = (char*)d_ws;
    size_t off = 0;
    auto alloc = [&](size_t b) {
        void* p = ws + off;
        off = (off + b + 255) & ~(size_t)255;
        return p;
    };
    float*    x      = (float*)alloc((size_t)NN * HH * 4);       //   8 MB
    float*    vecA   = (float*)alloc((size_t)NN * 768 * 4);      //  24 MB  \ adjacent:
    u16*      vb     = (u16*)alloc((size_t)NN * 768 * 2);        //  12 MB  / joint zero
    float*    vecM   = (float*)alloc((size_t)NN * 768 * 4);      //  24 MB
    u16*      xlnb   = (u16*)alloc((size_t)NN * HH * 2);         //   4 MB (alias xb)
    u16*      t1b    = (u16*)alloc((size_t)NN * HH * 2);         //   4 MB (alias h1b)
    u16*      xhb    = (u16*)alloc((size_t)NN * 768 * 2);        //  12 MB (alias hcatb)
    float*    vdot   = (float*)alloc((size_t)NN * HH * 4);       //   8 MB (alias heng)
    u16*      vpb    = (u16*)alloc((size_t)NN * 1536 * 2);       //  24 MB
    u16*      houtb  = (u16*)alloc((size_t)NN * 768 * 2);        //  12 MB
    float*    ev     = (float*)alloc((size_t)EE * 4 * 4);        //   2 MB
    int*      deg    = (int*)alloc((size_t)NN * 4);
    int*      row_ptr= (int*)alloc((size_t)(NN + 1) * 4);
    int*      fill   = (int*)alloc((size_t)NN * 4);
    int*      dorder = (int*)alloc((size_t)NN * 4);
    int*      srcp   = (int*)alloc((size_t)EE * 4);
    float4*   evp    = (float4*)alloc((size_t)EE * 16);          //   2 MB
    int*      kptab  = (int*)alloc((size_t)EE * 4);              // 0.5 MB
    unsigned* gtab   = (unsigned*)alloc((size_t)EE * 16);        //   2 MB (bf16 pairs)
    u16* xp_w1T   = (u16*)alloc((size_t)3 * 256 * 256 * 2);
    u16* xp_w2T   = (u16*)alloc((size_t)3 * 768 * 256 * 2);
    u16* rbf_wP   = (u16*)alloc((size_t)3 * 128 * 768 * 2);      // pair-interleaved bf16
    u16* vec_wT   = (u16*)alloc((size_t)3 * 512 * 256 * 2);
    u16* xv_w1T   = (u16*)alloc((size_t)3 * 256 * 512 * 2);
    u16* xv_w2T   = (u16*)alloc((size_t)3 * 768 * 256 * 2);
    u16* oe_w1T   = (u16*)alloc((size_t)128 * 256 * 2);
    (void)ws_size;

    u16*   h1b   = t1b;
    u16*   hcatb = xhb;
    float* heng  = vdot;
    u16*   xb    = xlnb;

    // ---- setup ----
    k_wt_all<<<2432, 256, 0, stream>>>(xp_w1, xp_w2, rbf_w, vec_w, xv_w1, xv_w2, oe_w1,
                                       xp_w1T, xp_w2T, rbf_wP, vec_wT, xv_w1T, xv_w2T, oe_w1T);
    k_zero<<<(36 * 1024 * 1024 / 16 + 255) / 256, 256, 0, stream>>>(vecA, 36 * 1024 * 1024 / 16);
    k_zero<<<8, 256, 0, stream>>>((float*)deg, NN / 4);
    k_init_ln<<<NN, 256, 0, stream>>>(atom_emb, z, ln_w, ln_b, x, xlnb);
    k_geom_hist<<<EE / 256, 256, 0, stream>>>(pos, ei, ev, deg);
    k_scan_sort<<<1, 256, 0, stream>>>(deg, row_ptr, fill, dorder);
    k_scatter<<<EE / 256, 256, 0, stream>>>(ei, ev, fill, srcp, evp, kptab, gtab);

    for (int l = 0; l < LL; ++l) {
        // ---- PaiNNMessage ----
        k_gemm<0, 1, 1><<<dim3(2, NN / 128), 256, 0, stream>>>(
            xlnb, xp_w1T + (size_t)l * 256 * 256, xp_b1 + l * HH, t1b, NN, 256, 256);
        k_gemm<0, 1, 0><<<dim3(6, NN / 128), 256, 0, stream>>>(
            t1b, xp_w2T + (size_t)l * 768 * 256, xp_b2 + l * 768, xhb, NN, 256, 768);
        k_msg<<<NN / MSG_WAVES, 1024, 0, stream>>>(
            xhb, vb, srcp, evp, row_ptr, kptab, gtab,
            rbf_wP + (size_t)l * 128 * 768, rbf_b + l * 768, x, vecA, vecM, dorder);

        // ---- PaiNNUpdate ----
        k_gemm<1, 1, 0><<<dim3(4, 3 * NN / 128), 256, 0, stream>>>(
            vecM, vec_wT + (size_t)l * 512 * 256, nullptr, vpb, 3 * NN, 256, 512);
        k_vecdot<<<NN, 256, 0, stream>>>(vpb, x, vdot, hcatb);
        k_gemm<0, 1, 1><<<dim3(2, NN / 128), 256, 0, stream>>>(
            hcatb, xv_w1T + (size_t)l * 256 * 512, xv_b1 + l * HH, h1b, NN, 512, 256);
        k_gemm<0, 1, 0><<<dim3(6, NN / 128), 256, 0, stream>>>(
            h1b, xv_w2T + (size_t)l * 768 * 256, xv_b2 + l * 768, houtb, NN, 256, 768);
        bool last = (l == LL - 1);
        k_update_out<<<NN, 256, 0, stream>>>(
            houtb, vdot, vpb, x, vecM, vecA, vb,
            last ? nullptr : ln_w + (l + 1) * HH,
            last ? nullptr : ln_b + (l + 1) * HH, xlnb);
    }

    // ---- energy head ----
    k_gemm<0, 0, 1><<<dim3(1, NN / 128), 256, 0, stream>>>(
        xb, oe_w1T, oe_b1, heng, NN, 256, 128);
    k_zero<<<1, 256, 0, stream>>>(out, NGG / 4);
    k_energy2<<<32, 256, 0, stream>>>(heng, oe_w2, oe_b2, batch, out);
}

// Round 18
// 790.706 us; speedup vs baseline: 1.0363x; 1.0151x over previous
//
#include <hip/hip_runtime.h>
#include <hip/hip_bf16.h>
#include <math.h>

#define NN 8192
#define EE 131072
#define HH 256
#define LL 3
#define RR 128
#define NGG 64
#define MSG_WAVES 16         // waves per k_msg block (1024 threads)

typedef __attribute__((ext_vector_type(8))) short bf16x8;
typedef __attribute__((ext_vector_type(4))) float f32x4;
typedef unsigned short u16;

#if defined(__has_builtin)
#if __has_builtin(__builtin_amdgcn_fdot2_f32_bf16)
#define HAVE_FDOT2 1
typedef __attribute__((ext_vector_type(2))) __bf16 bf16x2_t;
union BU { unsigned u; bf16x2_t v; };
#endif
#if __has_builtin(__builtin_amdgcn_global_load_lds)
#define HAVE_GLL 1
#endif
#endif

union U4 { ushort4 v; unsigned short a[4]; };
union U8 { uint4 v; unsigned short a[8]; unsigned w[4]; };

__device__ __forceinline__ float silu(float v) { return v / (1.0f + expf(-v)); }
__device__ __forceinline__ float b2f(unsigned short u) { return __uint_as_float(((unsigned)u) << 16); }
__device__ __forceinline__ unsigned short f2b(float f) {
    unsigned u = __float_as_uint(f);
    u += 0x7fff + ((u >> 16) & 1);
    return (unsigned short)(u >> 16);
}

constexpr float kInvSqrt2 = 0.70710678118654752440f;
constexpr float kInvSqrt3 = 0.57735026918962576451f;
constexpr float kInvSqrtH = 0.0625f; // 1/sqrt(256)

// ---------------- utility ----------------
__global__ void k_zero(float* __restrict__ p, int n4) {
    int i = blockIdx.x * 256 + threadIdx.x;
    if (i < n4) ((float4*)p)[i] = make_float4(0.f, 0.f, 0.f, 0.f);
}

// ---------------- ALL weight prep in one launch ----------------
// transpose in[K,N] fp32 -> out[N,K] bf16; rbf_w: row-PAIR interleaved k-major bf16
// rbf layout: dst[(k>>1)*1536 + n*2 + (k&1)]
__global__ __launch_bounds__(256) void k_wt_all(
    const float* __restrict__ xp_w1, const float* __restrict__ xp_w2,
    const float* __restrict__ rbf_w, const float* __restrict__ vec_w,
    const float* __restrict__ xv_w1, const float* __restrict__ xv_w2,
    const float* __restrict__ oe_w1,
    u16* __restrict__ xp_w1T, u16* __restrict__ xp_w2T, u16* __restrict__ rbf_wP,
    u16* __restrict__ vec_wT, u16* __restrict__ xv_w1T, u16* __restrict__ xv_w2T,
    u16* __restrict__ oe_w1T) {
    int bid = blockIdx.x;
    const float* src; u16* dst; int K, N, t, pairmode = 0;
    if (bid < 2400) {
        int l = bid / 800, r = bid % 800;
        if (r < 64)       { src = xp_w1 + (size_t)l * 65536;  dst = xp_w1T + (size_t)l * 65536;  K = 256; N = 256; t = r; }
        else if (r < 256) { src = xp_w2 + (size_t)l * 196608; dst = xp_w2T + (size_t)l * 196608; K = 256; N = 768; t = r - 64; }
        else if (r < 352) { src = rbf_w + (size_t)l * 98304;  dst = rbf_wP + (size_t)l * 98304;  K = 128; N = 768; t = r - 256; pairmode = 1; }
        else if (r < 480) { src = vec_w + (size_t)l * 131072; dst = vec_wT + (size_t)l * 131072; K = 256; N = 512; t = r - 352; }
        else if (r < 608) { src = xv_w1 + (size_t)l * 131072; dst = xv_w1T + (size_t)l * 131072; K = 512; N = 256; t = r - 480; }
        else              { src = xv_w2 + (size_t)l * 196608; dst = xv_w2T + (size_t)l * 196608; K = 256; N = 768; t = r - 608; }
    } else {
        src = oe_w1; dst = oe_w1T; K = 256; N = 128; t = bid - 2400;
    }
    int nx = N >> 5;
    int bn = (t % nx) * 32, bk = (t / nx) * 32;
    int tx = threadIdx.x & 31, ty = threadIdx.x >> 5;   // 32 x 8
    if (pairmode) {
#pragma unroll
        for (int i = 0; i < 32; i += 8) {
            int k = bk + ty + i, n = bn + tx;
            dst[(size_t)(k >> 1) * 1536 + n * 2 + (k & 1)] = f2b(src[(size_t)k * N + n]);
        }
        return;
    }
    __shared__ float tile[32][33];
#pragma unroll
    for (int i = 0; i < 32; i += 8)
        tile[ty + i][tx] = src[(size_t)(bk + ty + i) * N + bn + tx];
    __syncthreads();
#pragma unroll
    for (int i = 0; i < 32; i += 8)
        dst[(size_t)(bn + ty + i) * K + bk + tx] = f2b(tile[tx][ty + i]);
}

// ---------------- init: x = atom_emb[z], + LayerNorm(ln[0]) -> xlnb ----------------
__global__ void k_init_ln(const float* __restrict__ emb, const int* __restrict__ z,
                          const float* __restrict__ w, const float* __restrict__ b,
                          float* __restrict__ x, u16* __restrict__ xlnb) {
    int n = blockIdx.x, t = threadIdx.x;
    float v = emb[z[n] * HH + t];
    x[(size_t)n * HH + t] = v;
    float s = v, q = v * v;
#pragma unroll
    for (int m = 32; m >= 1; m >>= 1) {
        s += __shfl_xor(s, m, 64);
        q += __shfl_xor(q, m, 64);
    }
    __shared__ float s_sum[4], s_sq[4];
    int wid = t >> 6;
    if ((t & 63) == 0) { s_sum[wid] = s; s_sq[wid] = q; }
    __syncthreads();
    float S = s_sum[0] + s_sum[1] + s_sum[2] + s_sum[3];
    float Q = s_sq[0] + s_sq[1] + s_sq[2] + s_sq[3];
    float mu = S * (1.0f / HH);
    float var = Q * (1.0f / HH) - mu * mu;
    float rs = rsqrtf(var + 1e-5f);
    xlnb[(size_t)n * HH + t] = f2b((v - mu) * rs * w[t] + b[t]);
}

// ---------------- edge geometry + degree histogram (fused) ----------------
__global__ void k_geom_hist(const float* __restrict__ pos, const int* __restrict__ ei,
                            float* __restrict__ ev, int* __restrict__ deg) {
    int e = blockIdx.x * 256 + threadIdx.x;
    if (e >= EE) return;
    int s = ei[e], d = ei[EE + e];
    float rx = pos[s * 3 + 0] - pos[d * 3 + 0];
    float ry = pos[s * 3 + 1] - pos[d * 3 + 1];
    float rz = pos[s * 3 + 2] - pos[d * 3 + 2];
    float dist = sqrtf(rx * rx + ry * ry + rz * rz);
    float inv = 1.0f / dist;
    ((float4*)ev)[e] = make_float4(rx * inv, ry * inv, rz * inv, dist);
    atomicAdd(&deg[d], 1);
}

// ---------------- scan (CSR row_ptr) + degree bucket-sort, one block ---------------
__global__ void k_scan_sort(const int* __restrict__ deg, int* __restrict__ row_ptr,
                            int* __restrict__ fill, int* __restrict__ dorder) {
    __shared__ int buf[256];
    __shared__ int carry_s;
    int t = threadIdx.x;
    if (t == 0) carry_s = 0;
    __syncthreads();
    for (int r = 0; r < NN; r += 256) {
        int v = deg[r + t];
        buf[t] = v;
        __syncthreads();
        for (int ofs = 1; ofs < 256; ofs <<= 1) {
            int add = (t >= ofs) ? buf[t - ofs] : 0;
            __syncthreads();
            buf[t] += add;
            __syncthreads();
        }
        int excl = buf[t] - v;
        int carry = carry_s;
        row_ptr[r + t] = carry + excl;
        fill[r + t] = carry + excl;
        __syncthreads();
        if (t == 255) carry_s = carry + buf[t];
        __syncthreads();
    }
    if (t == 0) row_ptr[NN] = carry_s;
    __syncthreads();
    __shared__ int bins[256];
    __shared__ int base[256];
    bins[t] = 0;
    __syncthreads();
    for (int d = t; d < NN; d += 256) {
        int b = deg[d]; b = b > 255 ? 255 : b;
        atomicAdd(&bins[b], 1);
    }
    __syncthreads();
    if (t == 0) {
        int acc = 0;
        for (int k = 255; k >= 0; --k) { base[k] = acc; acc += bins[k]; }
    }
    __syncthreads();
    bins[t] = 0;
    __syncthreads();
    for (int d = t; d < NN; d += 256) {
        int b = deg[d]; b = b > 255 ? 255 : b;
        int p = atomicAdd(&bins[b], 1);
        dorder[base[b] + p] = d;
    }
}

// scatter + gaussian window: 8 rows, EVEN-aligned k0; gtab packed bf16 pairs (16B)
__global__ void k_scatter(const int* __restrict__ ei, const float* __restrict__ ev,
                          int* __restrict__ fill, int* __restrict__ srcp,
                          float4* __restrict__ evp, int* __restrict__ kptab,
                          unsigned* __restrict__ gtab) {
    int e = blockIdx.x * 256 + threadIdx.x;
    if (e >= EE) return;
    int d = ei[EE + e];
    int pos = atomicAdd(&fill[d], 1);
    float4 e4 = ((const float4*)ev)[e];
    srcp[pos] = ei[e];
    evp[pos] = e4;
    const float step = 12.0f / 127.0f;
    const float coeff = -0.5f / (step * step);
    float dist = e4.w;
    int k0 = ((int)floorf(dist / step) - 3) & ~1;   // even-aligned
    k0 = k0 < 0 ? 0 : (k0 > 120 ? 120 : k0);
    float g[8];
#pragma unroll
    for (int k = 0; k < 8; ++k) {
        float t = dist - (k0 + k) * step;
        g[k] = expf(coeff * t * t);
    }
    kptab[pos] = k0 >> 1;
    unsigned g0 = (unsigned)f2b(g[0]) | ((unsigned)f2b(g[1]) << 16);
    unsigned g1 = (unsigned)f2b(g[2]) | ((unsigned)f2b(g[3]) << 16);
    unsigned g2 = (unsigned)f2b(g[4]) | ((unsigned)f2b(g[5]) << 16);
    unsigned g3 = (unsigned)f2b(g[6]) | ((unsigned)f2b(g[7]) << 16);
    ((uint4*)gtab)[pos] = make_uint4(g0, g1, g2, g3);
}

// ---------------- bf16 MFMA GEMM: C = act(A[M,K] @ BT[N,K]^T + bias) ----------------
// Staging via global_load_lds width=16 when available (m97 lever).
template <int OUT_BF16, int ACT>
__global__ __launch_bounds__(256) void k_gemm(
    const u16* __restrict__ A, const u16* __restrict__ BT,
    const float* __restrict__ bias, void* __restrict__ C, int M, int K, int N) {
    __shared__ u16 As[4096];   // [128 rows][32 k] bf16 = 8 KB
    __shared__ u16 Bs[4096];
    int tid = threadIdx.x;
    int wave = tid >> 6, lane = tid & 63;
    int bm = blockIdx.y * 128, bn = blockIdx.x * 128;
    int wm = (wave >> 1) * 64, wn = (wave & 1) * 64;
    int lm = lane & 15;
    int kg = lane >> 4;
    f32x4 acc[4][4] = {};

    for (int k0 = 0; k0 < K; k0 += 32) {
#pragma unroll
        for (int it = 0; it < 2; ++it) {
            int idx = it * 256 + tid;
            int r = idx >> 2, seg = idx & 3;
#ifdef HAVE_GLL
            __builtin_amdgcn_global_load_lds(
                (const unsigned*)&A[(size_t)(bm + r) * K + k0 + seg * 8],
                (unsigned*)&As[idx * 8], 16, 0, 0);
            __builtin_amdgcn_global_load_lds(
                (const unsigned*)&BT[(size_t)(bn + r) * K + k0 + seg * 8],
                (unsigned*)&Bs[idx * 8], 16, 0, 0);
#else
            *(uint4*)&As[idx * 8] = *(const uint4*)&A[(size_t)(bm + r) * K + k0 + seg * 8];
            *(uint4*)&Bs[idx * 8] = *(const uint4*)&BT[(size_t)(bn + r) * K + k0 + seg * 8];
#endif
        }
        __syncthreads();
        bf16x8 af[4], bfr[4];
#pragma unroll
        for (int i = 0; i < 4; ++i)
            af[i] = *(const bf16x8*)&As[(wm + i * 16 + lm) * 32 + kg * 8];
#pragma unroll
        for (int j = 0; j < 4; ++j)
            bfr[j] = *(const bf16x8*)&Bs[(wn + j * 16 + lm) * 32 + kg * 8];
#pragma unroll
        for (int i = 0; i < 4; ++i)
#pragma unroll
            for (int j = 0; j < 4; ++j)
                acc[i][j] = __builtin_amdgcn_mfma_f32_16x16x32_bf16(af[i], bfr[j], acc[i][j], 0, 0, 0);
        __syncthreads();
    }

#pragma unroll
    for (int j = 0; j < 4; ++j) {
        int col = bn + wn + j * 16 + lm;
        float bv = bias ? bias[col] : 0.f;
#pragma unroll
        for (int i = 0; i < 4; ++i) {
            int row0 = bm + wm + i * 16 + kg * 4;
#pragma unroll
            for (int r = 0; r < 4; ++r) {
                float v = acc[i][j][r] + bv;
                if (ACT) v = silu(v);
                if (OUT_BF16)
                    ((u16*)C)[(size_t)(row0 + r) * N + col] = f2b(v);
                else
                    ((float*)C)[(size_t)(row0 + r) * N + col] = v;
            }
        }
    }
}

// ---------------- fused message pass v12: pair-panel + v_dot2_f32_bf16 combine -----
// 16-wave 64KB-panel blocks, degree-sorted dsts. Epilogue also emits vecMb (bf16)
// so the vec GEMM reads a bf16 A (enables global_load_lds staging there).
__global__ __launch_bounds__(1024) void k_msg(
    const u16* __restrict__ xhb, const u16* __restrict__ vinb,
    const int* __restrict__ srcp, const float4* __restrict__ evp,
    const int* __restrict__ row_ptr, const int* __restrict__ kptab,
    const unsigned* __restrict__ gtab, const u16* __restrict__ WP /*pair-interleaved*/,
    const float* __restrict__ rbias, float* __restrict__ x,
    const float* __restrict__ vin, float* __restrict__ vecM,
    u16* __restrict__ vecMb, const int* __restrict__ dorder) {
    __shared__ u16 Wp[64 * 512];    // 64 KB: [64 row-pairs][256 cols][2]
    int tid = threadIdx.x;
    int wave = tid >> 6, lane = tid & 63;
    int c0 = lane * 4;
    int d = dorder[blockIdx.x * MSG_WAVES + wave];
    int E0 = row_ptr[d], E1 = row_ptr[d + 1];
    float accv[3][4] = {};          // persists across panels 1,2

#pragma unroll
    for (int p = 0; p < 3; ++p) {
        __syncthreads();
#pragma unroll
        for (int it = 0; it < 4; ++it) {        // cooperative 64KB panel load
            int idx = it * 1024 + tid;          // 4096 uint4
            int r = idx >> 6;                   // 64 row-pairs, 64 uint4/pair
            int c8 = (idx & 63) * 8;
            *(uint4*)&Wp[r * 512 + c8] =
                *(const uint4*)&WP[(size_t)r * 1536 + p * 512 + c8];
        }
        __syncthreads();
        float4 bb = ((const float4*)(rbias + p * 256))[lane];
        float bias4[4] = {bb.x, bb.y, bb.z, bb.w};
        float accx[4] = {};
        for (int j = E0; j < E1; ++j) {
            int s = srcp[j];
            int kp = kptab[j];
            uint4 gt = ((const uint4*)gtab)[j];
            unsigned gp[4] = {gt.x, gt.y, gt.z, gt.w};
            float rr[4] = {bias4[0], bias4[1], bias4[2], bias4[3]};
#pragma unroll
            for (int p2 = 0; p2 < 4; ++p2) {
                U8 w;
                w.v = *(const uint4*)&Wp[(kp + p2) * 512 + c0 * 2];  // ds_read_b128
#ifdef HAVE_FDOT2
                BU gv; gv.u = gp[p2];
#pragma unroll
                for (int c = 0; c < 4; ++c) {
                    BU wv; wv.u = w.w[c];
                    rr[c] = __builtin_amdgcn_fdot2_f32_bf16(wv.v, gv.v, rr[c], false);
                }
#else
                float ge = b2f((u16)(gp[p2] & 0xffff));
                float go = b2f((u16)(gp[p2] >> 16));
#pragma unroll
                for (int c = 0; c < 4; ++c)
                    rr[c] += ge * b2f(w.a[2 * c]) + go * b2f(w.a[2 * c + 1]);
#endif
            }
            if (p == 0) {
                U4 X; X.v = *(const ushort4*)(xhb + (size_t)s * 768 + c0);
#pragma unroll
                for (int c = 0; c < 4; ++c) accx[c] += b2f(X.a[c]) * rr[c];
            } else if (p == 1) {
                U4 X, V0, V1, V2;
                X.v = *(const ushort4*)(xhb + (size_t)s * 768 + 256 + c0);
                V0.v = *(const ushort4*)(vinb + (size_t)s * 768 + c0);
                V1.v = *(const ushort4*)(vinb + (size_t)s * 768 + 256 + c0);
                V2.v = *(const ushort4*)(vinb + (size_t)s * 768 + 512 + c0);
#pragma unroll
                for (int c = 0; c < 4; ++c) {
                    float m1 = b2f(X.a[c]) * rr[c] * kInvSqrt3;
                    accv[0][c] += b2f(V0.a[c]) * m1;
                    accv[1][c] += b2f(V1.a[c]) * m1;
                    accv[2][c] += b2f(V2.a[c]) * m1;
                }
            } else {
                U4 X; X.v = *(const ushort4*)(xhb + (size_t)s * 768 + 512 + c0);
                float4 ev4 = evp[j];
#pragma unroll
                for (int c = 0; c < 4; ++c) {
                    float m2 = b2f(X.a[c]) * rr[c];
                    accv[0][c] += m2 * ev4.x;
                    accv[1][c] += m2 * ev4.y;
                    accv[2][c] += m2 * ev4.z;
                }
            }
        }
        if (p == 0) {
            size_t xi = (size_t)d * 256 + c0;
            float4 xv = *(const float4*)&x[xi];
            xv.x = (xv.x + accx[0]) * kInvSqrt2;
            xv.y = (xv.y + accx[1]) * kInvSqrt2;
            xv.z = (xv.z + accx[2]) * kInvSqrt2;
            xv.w = (xv.w + accx[3]) * kInvSqrt2;
            *(float4*)&x[xi] = xv;
        }
    }
    // epilogue: vecM = vin + dvec * invSqrtH  (+ bf16 copy for the vec GEMM)
#pragma unroll
    for (int k = 0; k < 3; ++k) {
        size_t idx = (size_t)d * 768 + k * 256 + c0;
        float4 vv = *(const float4*)&vin[idx];
        vv.x += accv[k][0] * kInvSqrtH;
        vv.y += accv[k][1] * kInvSqrtH;
        vv.z += accv[k][2] * kInvSqrtH;
        vv.w += accv[k][3] * kInvSqrtH;
        *(float4*)&vecM[idx] = vv;
        ushort4 u;
        u.x = f2b(vv.x); u.y = f2b(vv.y); u.z = f2b(vv.z); u.w = f2b(vv.w);
        *(ushort4*)&vecMb[idx] = u;
    }
}

// ---------------- vec_dot + hcat(bf16) = [x, vnorm]; vp in bf16 -------------------
__global__ void k_vecdot(const u16* __restrict__ vp, const float* __restrict__ x,
                         float* __restrict__ vec_dot, u16* __restrict__ hcat) {
    int i = blockIdx.x * 256 + threadIdx.x;  // N*H
    int n = i >> 8, c = i & 255;
    const u16* p = vp + (size_t)n * 1536;
    float dsum = 0.f, qsum = 0.f;
#pragma unroll
    for (int k = 0; k < 3; ++k) {
        float v1 = b2f(p[k * 512 + c]);
        float v2 = b2f(p[k * 512 + 256 + c]);
        dsum += v1 * v2;
        qsum += v2 * v2;
    }
    vec_dot[i] = dsum * kInvSqrtH;
    hcat[(size_t)n * 512 + c] = f2b(x[i]);
    hcat[(size_t)n * 512 + 256 + c] = f2b(sqrtf(qsum + 1e-8f));
}

// ---------------- update epilogue + fused LayerNorm for next layer ----------------
__global__ void k_update_out(const u16* __restrict__ hout, const float* __restrict__ vec_dot,
                             const u16* __restrict__ vp, float* __restrict__ x,
                             const float* __restrict__ vecM, float* __restrict__ vfin,
                             u16* __restrict__ vb,
                             const float* __restrict__ lnw, const float* __restrict__ lnb,
                             u16* __restrict__ xout) {
    int n = blockIdx.x, t = threadIdx.x;
    size_t i = (size_t)n * 256 + t;
    float xv1 = b2f(hout[(size_t)n * 768 + t]);
    float xv2 = b2f(hout[(size_t)n * 768 + 256 + t]);
    float xv3 = b2f(hout[(size_t)n * 768 + 512 + t]);
    float dxv = (xv1 + xv2 * vec_dot[i]) * kInvSqrt2;
    float nx = (x[i] + dxv) * kInvSqrt2;
    x[i] = nx;
#pragma unroll
    for (int k = 0; k < 3; ++k) {
        size_t idx = (size_t)n * 768 + k * 256 + t;
        float nv = vecM[idx] + xv3 * b2f(vp[(size_t)n * 1536 + k * 512 + t]);
        vfin[idx] = nv;
        vb[idx] = f2b(nv);
    }
    if (lnw) {
        float s = nx, q = nx * nx;
#pragma unroll
        for (int m = 32; m >= 1; m >>= 1) {
            s += __shfl_xor(s, m, 64);
            q += __shfl_xor(q, m, 64);
        }
        __shared__ float s_sum[4], s_sq[4];
        int wid = t >> 6;
        if ((t & 63) == 0) { s_sum[wid] = s; s_sq[wid] = q; }
        __syncthreads();
        float S = s_sum[0] + s_sum[1] + s_sum[2] + s_sum[3];
        float Q = s_sq[0] + s_sq[1] + s_sq[2] + s_sq[3];
        float mu = S * (1.0f / HH);
        float var = Q * (1.0f / HH) - mu * mu;
        float rs = rsqrtf(var + 1e-5f);
        xout[i] = f2b((nx - mu) * rs * lnw[t] + lnb[t]);
    } else {
        xout[i] = f2b(nx);
    }
}

// ---------------- energy reduce ----------------
__global__ void k_energy2(const float* __restrict__ h, const float* __restrict__ w2,
                          const float* __restrict__ b2, const int* __restrict__ batch,
                          float* __restrict__ out) {
    __shared__ float g[NGG];
    int t = threadIdx.x;
    if (t < NGG) g[t] = 0.f;
    __syncthreads();
    int a = blockIdx.x * 256 + t;
    const float4* hr = (const float4*)(h + (size_t)a * 128);
    const float4* w4 = (const float4*)w2;
    float acc = 0.f;
#pragma unroll 8
    for (int i = 0; i < 32; ++i) {
        float4 hv = hr[i], wv = w4[i];
        acc += hv.x * wv.x + hv.y * wv.y + hv.z * wv.z + hv.w * wv.w;
    }
    acc += b2[0];
    atomicAdd(&g[batch[a]], acc);
    __syncthreads();
    if (t < NGG && g[t] != 0.f) atomicAdd(&out[t], g[t]);
}

extern "C" void kernel_launch(void* const* d_in, const int* in_sizes, int n_in,
                              void* d_out, int out_size, void* d_ws, size_t ws_size,
                              hipStream_t stream) {
    const float* pos      = (const float*)d_in[0];
    const float* atom_emb = (const float*)d_in[1];
    const float* ln_w     = (const float*)d_in[2];
    const float* ln_b     = (const float*)d_in[3];
    const float* xp_w1    = (const float*)d_in[4];
    const float* xp_b1    = (const float*)d_in[5];
    const float* xp_w2    = (const float*)d_in[6];
    const float* xp_b2    = (const float*)d_in[7];
    const float* rbf_w    = (const float*)d_in[8];
    const float* rbf_b    = (const float*)d_in[9];
    const float* vec_w    = (const float*)d_in[10];
    const float* xv_w1    = (const float*)d_in[11];
    const float* xv_b1    = (const float*)d_in[12];
    const float* xv_w2    = (const float*)d_in[13];
    const float* xv_b2    = (const float*)d_in[14];
    const float* oe_w1    = (const float*)d_in[15];
    const float* oe_b1    = (const float*)d_in[16];
    const float* oe_w2    = (const float*)d_in[17];
    const float* oe_b2    = (const float*)d_in[18];
    const int*   z        = (const int*)d_in[19];
    const int*   ei       = (const int*)d_in[20];
    const int*   batch    = (const int*)d_in[21];
    float* out = (float*)d_out;

    char* ws = (char*)d_ws;
    size_t off = 0;
    auto alloc = [&](size_t b) {
        void* p = ws + off;
        off = (off + b + 255) & ~(size_t)255;
        return p;
    };
    float*    x      = (float*)alloc((size_t)NN * HH * 4);       //   8 MB
    float*    vecA   = (float*)alloc((size_t)NN * 768 * 4);      //  24 MB  \ adjacent:
    u16*      vb     = (u16*)alloc((size_t)NN * 768 * 2);        //  12 MB  / joint zero
    float*    vecM   = (float*)alloc((size_t)NN * 768 * 4);      //  24 MB
    u16*      vecMb  = (u16*)alloc((size_t)NN * 768 * 2);        //  12 MB
    u16*      xlnb   = (u16*)alloc((size_t)NN * HH * 2);         //   4 MB (alias xb)
    u16*      t1b    = (u16*)alloc((size_t)NN * HH * 2);         //   4 MB (alias h1b)
    u16*      xhb    = (u16*)alloc((size_t)NN * 768 * 2);        //  12 MB (alias hcatb)
    float*    vdot   = (float*)alloc((size_t)NN * HH * 4);       //   8 MB (alias heng)
    u16*      vpb    = (u16*)alloc((size_t)NN * 1536 * 2);       //  24 MB
    u16*      houtb  = (u16*)alloc((size_t)NN * 768 * 2);        //  12 MB
    float*    ev     = (float*)alloc((size_t)EE * 4 * 4);        //   2 MB
    int*      deg    = (int*)alloc((size_t)NN * 4);
    int*      row_ptr= (int*)alloc((size_t)(NN + 1) * 4);
    int*      fill   = (int*)alloc((size_t)NN * 4);
    int*      dorder = (int*)alloc((size_t)NN * 4);
    int*      srcp   = (int*)alloc((size_t)EE * 4);
    float4*   evp    = (float4*)alloc((size_t)EE * 16);          //   2 MB
    int*      kptab  = (int*)alloc((size_t)EE * 4);              // 0.5 MB
    unsigned* gtab   = (unsigned*)alloc((size_t)EE * 16);        //   2 MB (bf16 pairs)
    u16* xp_w1T   = (u16*)alloc((size_t)3 * 256 * 256 * 2);
    u16* xp_w2T   = (u16*)alloc((size_t)3 * 768 * 256 * 2);
    u16* rbf_wP   = (u16*)alloc((size_t)3 * 128 * 768 * 2);      // pair-interleaved bf16
    u16* vec_wT   = (u16*)alloc((size_t)3 * 512 * 256 * 2);
    u16* xv_w1T   = (u16*)alloc((size_t)3 * 256 * 512 * 2);
    u16* xv_w2T   = (u16*)alloc((size_t)3 * 768 * 256 * 2);
    u16* oe_w1T   = (u16*)alloc((size_t)128 * 256 * 2);
    (void)ws_size;

    u16*   h1b   = t1b;
    u16*   hcatb = xhb;
    float* heng  = vdot;
    u16*   xb    = xlnb;

    // ---- setup ----
    k_wt_all<<<2432, 256, 0, stream>>>(xp_w1, xp_w2, rbf_w, vec_w, xv_w1, xv_w2, oe_w1,
                                       xp_w1T, xp_w2T, rbf_wP, vec_wT, xv_w1T, xv_w2T, oe_w1T);
    k_zero<<<(36 * 1024 * 1024 / 16 + 255) / 256, 256, 0, stream>>>(vecA, 36 * 1024 * 1024 / 16);
    k_zero<<<8, 256, 0, stream>>>((float*)deg, NN / 4);
    k_init_ln<<<NN, 256, 0, stream>>>(atom_emb, z, ln_w, ln_b, x, xlnb);
    k_geom_hist<<<EE / 256, 256, 0, stream>>>(pos, ei, ev, deg);
    k_scan_sort<<<1, 256, 0, stream>>>(deg, row_ptr, fill, dorder);
    k_scatter<<<EE / 256, 256, 0, stream>>>(ei, ev, fill, srcp, evp, kptab, gtab);

    for (int l = 0; l < LL; ++l) {
        // ---- PaiNNMessage ----
        k_gemm<1, 1><<<dim3(2, NN / 128), 256, 0, stream>>>(
            xlnb, xp_w1T + (size_t)l * 256 * 256, xp_b1 + l * HH, t1b, NN, 256, 256);
        k_gemm<1, 0><<<dim3(6, NN / 128), 256, 0, stream>>>(
            t1b, xp_w2T + (size_t)l * 768 * 256, xp_b2 + l * 768, xhb, NN, 256, 768);
        k_msg<<<NN / MSG_WAVES, 1024, 0, stream>>>(
            xhb, vb, srcp, evp, row_ptr, kptab, gtab,
            rbf_wP + (size_t)l * 128 * 768, rbf_b + l * 768, x, vecA, vecM, vecMb, dorder);

        // ---- PaiNNUpdate ----
        k_gemm<1, 0><<<dim3(4, 3 * NN / 128), 256, 0, stream>>>(
            vecMb, vec_wT + (size_t)l * 512 * 256, nullptr, vpb, 3 * NN, 256, 512);
        k_vecdot<<<NN, 256, 0, stream>>>(vpb, x, vdot, hcatb);
        k_gemm<1, 1><<<dim3(2, NN / 128), 256, 0, stream>>>(
            hcatb, xv_w1T + (size_t)l * 256 * 512, xv_b1 + l * HH, h1b, NN, 512, 256);
        k_gemm<1, 0><<<dim3(6, NN / 128), 256, 0, stream>>>(
            h1b, xv_w2T + (size_t)l * 768 * 256, xv_b2 + l * 768, houtb, NN, 256, 768);
        bool last = (l == LL - 1);
        k_update_out<<<NN, 256, 0, stream>>>(
            houtb, vdot, vpb, x, vecM, vecA, vb,
            last ? nullptr : ln_w + (l + 1) * HH,
            last ? nullptr : ln_b + (l + 1) * HH, xlnb);
    }

    // ---- energy head ----
    k_gemm<0, 1><<<dim3(1, NN / 128), 256, 0, stream>>>(
        xb, oe_w1T, oe_b1, heng, NN, 256, 128);
    k_zero<<<1, 256, 0, stream>>>(out, NGG / 4);
    k_energy2<<<32, 256, 0, stream>>>(heng, oe_w2, oe_b2, batch, out);
}

// Round 19
// 779.604 us; speedup vs baseline: 1.0511x; 1.0142x over previous
//
#include <hip/hip_runtime.h>
#include <hip/hip_bf16.h>
#include <math.h>

#define NN 8192
#define EE 131072
#define HH 256
#define LL 3
#define RR 128
#define NGG 64
#define MSG_WAVES 16         // waves per k_msg block (1024 threads)

typedef __attribute__((ext_vector_type(8))) short bf16x8;
typedef __attribute__((ext_vector_type(4))) float f32x4;
typedef unsigned short u16;

#if defined(__has_builtin)
#if __has_builtin(__builtin_amdgcn_fdot2_f32_bf16)
#define HAVE_FDOT2 1
typedef __attribute__((ext_vector_type(2))) __bf16 bf16x2_t;
union BU { unsigned u; bf16x2_t v; };
#endif
#if __has_builtin(__builtin_amdgcn_global_load_lds)
#define HAVE_GLL 1
#endif
#endif

union U4 { ushort4 v; unsigned short a[4]; };
union U8 { uint4 v; unsigned short a[8]; unsigned w[4]; };

__device__ __forceinline__ float silu(float v) { return v / (1.0f + expf(-v)); }
__device__ __forceinline__ float b2f(unsigned short u) { return __uint_as_float(((unsigned)u) << 16); }
__device__ __forceinline__ unsigned short f2b(float f) {
    unsigned u = __float_as_uint(f);
    u += 0x7fff + ((u >> 16) & 1);
    return (unsigned short)(u >> 16);
}

constexpr float kInvSqrt2 = 0.70710678118654752440f;
constexpr float kInvSqrt3 = 0.57735026918962576451f;
constexpr float kInvSqrtH = 0.0625f; // 1/sqrt(256)

// ---------------- utility ----------------
__global__ void k_zero(float* __restrict__ p, int n4) {
    int i = blockIdx.x * 256 + threadIdx.x;
    if (i < n4) ((float4*)p)[i] = make_float4(0.f, 0.f, 0.f, 0.f);
}

// ---------------- ALL weight prep in one launch ----------------
// transpose in[K,N] fp32 -> out[N,K] bf16; rbf_w: row-PAIR interleaved k-major bf16
__global__ __launch_bounds__(256) void k_wt_all(
    const float* __restrict__ xp_w1, const float* __restrict__ xp_w2,
    const float* __restrict__ rbf_w, const float* __restrict__ vec_w,
    const float* __restrict__ xv_w1, const float* __restrict__ xv_w2,
    const float* __restrict__ oe_w1,
    u16* __restrict__ xp_w1T, u16* __restrict__ xp_w2T, u16* __restrict__ rbf_wP,
    u16* __restrict__ vec_wT, u16* __restrict__ xv_w1T, u16* __restrict__ xv_w2T,
    u16* __restrict__ oe_w1T) {
    int bid = blockIdx.x;
    const float* src; u16* dst; int K, N, t, pairmode = 0;
    if (bid < 2400) {
        int l = bid / 800, r = bid % 800;
        if (r < 64)       { src = xp_w1 + (size_t)l * 65536;  dst = xp_w1T + (size_t)l * 65536;  K = 256; N = 256; t = r; }
        else if (r < 256) { src = xp_w2 + (size_t)l * 196608; dst = xp_w2T + (size_t)l * 196608; K = 256; N = 768; t = r - 64; }
        else if (r < 352) { src = rbf_w + (size_t)l * 98304;  dst = rbf_wP + (size_t)l * 98304;  K = 128; N = 768; t = r - 256; pairmode = 1; }
        else if (r < 480) { src = vec_w + (size_t)l * 131072; dst = vec_wT + (size_t)l * 131072; K = 256; N = 512; t = r - 352; }
        else if (r < 608) { src = xv_w1 + (size_t)l * 131072; dst = xv_w1T + (size_t)l * 131072; K = 512; N = 256; t = r - 480; }
        else              { src = xv_w2 + (size_t)l * 196608; dst = xv_w2T + (size_t)l * 196608; K = 256; N = 768; t = r - 608; }
    } else {
        src = oe_w1; dst = oe_w1T; K = 256; N = 128; t = bid - 2400;
    }
    int nx = N >> 5;
    int bn = (t % nx) * 32, bk = (t / nx) * 32;
    int tx = threadIdx.x & 31, ty = threadIdx.x >> 5;   // 32 x 8
    if (pairmode) {
#pragma unroll
        for (int i = 0; i < 32; i += 8) {
            int k = bk + ty + i, n = bn + tx;
            dst[(size_t)(k >> 1) * 1536 + n * 2 + (k & 1)] = f2b(src[(size_t)k * N + n]);
        }
        return;
    }
    __shared__ float tile[32][33];
#pragma unroll
    for (int i = 0; i < 32; i += 8)
        tile[ty + i][tx] = src[(size_t)(bk + ty + i) * N + bn + tx];
    __syncthreads();
#pragma unroll
    for (int i = 0; i < 32; i += 8)
        dst[(size_t)(bn + ty + i) * K + bk + tx] = f2b(tile[tx][ty + i]);
}

// ---------------- init: x = atom_emb[z], + LayerNorm(ln[0]) -> xlnb ----------------
__global__ void k_init_ln(const float* __restrict__ emb, const int* __restrict__ z,
                          const float* __restrict__ w, const float* __restrict__ b,
                          float* __restrict__ x, u16* __restrict__ xlnb) {
    int n = blockIdx.x, t = threadIdx.x;
    float v = emb[z[n] * HH + t];
    x[(size_t)n * HH + t] = v;
    float s = v, q = v * v;
#pragma unroll
    for (int m = 32; m >= 1; m >>= 1) {
        s += __shfl_xor(s, m, 64);
        q += __shfl_xor(q, m, 64);
    }
    __shared__ float s_sum[4], s_sq[4];
    int wid = t >> 6;
    if ((t & 63) == 0) { s_sum[wid] = s; s_sq[wid] = q; }
    __syncthreads();
    float S = s_sum[0] + s_sum[1] + s_sum[2] + s_sum[3];
    float Q = s_sq[0] + s_sq[1] + s_sq[2] + s_sq[3];
    float mu = S * (1.0f / HH);
    float var = Q * (1.0f / HH) - mu * mu;
    float rs = rsqrtf(var + 1e-5f);
    xlnb[(size_t)n * HH + t] = f2b((v - mu) * rs * w[t] + b[t]);
}

// ---------------- edge geometry + degree histogram (fused) ----------------
__global__ void k_geom_hist(const float* __restrict__ pos, const int* __restrict__ ei,
                            float* __restrict__ ev, int* __restrict__ deg) {
    int e = blockIdx.x * 256 + threadIdx.x;
    if (e >= EE) return;
    int s = ei[e], d = ei[EE + e];
    float rx = pos[s * 3 + 0] - pos[d * 3 + 0];
    float ry = pos[s * 3 + 1] - pos[d * 3 + 1];
    float rz = pos[s * 3 + 2] - pos[d * 3 + 2];
    float dist = sqrtf(rx * rx + ry * ry + rz * rz);
    float inv = 1.0f / dist;
    ((float4*)ev)[e] = make_float4(rx * inv, ry * inv, rz * inv, dist);
    atomicAdd(&deg[d], 1);
}

// ---------------- scan (CSR row_ptr) + degree bucket-sort, one block ---------------
__global__ void k_scan_sort(const int* __restrict__ deg, int* __restrict__ row_ptr,
                            int* __restrict__ fill, int* __restrict__ dorder) {
    __shared__ int buf[256];
    __shared__ int carry_s;
    int t = threadIdx.x;
    if (t == 0) carry_s = 0;
    __syncthreads();
    for (int r = 0; r < NN; r += 256) {
        int v = deg[r + t];
        buf[t] = v;
        __syncthreads();
        for (int ofs = 1; ofs < 256; ofs <<= 1) {
            int add = (t >= ofs) ? buf[t - ofs] : 0;
            __syncthreads();
            buf[t] += add;
            __syncthreads();
        }
        int excl = buf[t] - v;
        int carry = carry_s;
        row_ptr[r + t] = carry + excl;
        fill[r + t] = carry + excl;
        __syncthreads();
        if (t == 255) carry_s = carry + buf[t];
        __syncthreads();
    }
    if (t == 0) row_ptr[NN] = carry_s;
    __syncthreads();
    __shared__ int bins[256];
    __shared__ int base[256];
    bins[t] = 0;
    __syncthreads();
    for (int d = t; d < NN; d += 256) {
        int b = deg[d]; b = b > 255 ? 255 : b;
        atomicAdd(&bins[b], 1);
    }
    __syncthreads();
    if (t == 0) {
        int acc = 0;
        for (int k = 255; k >= 0; --k) { base[k] = acc; acc += bins[k]; }
    }
    __syncthreads();
    bins[t] = 0;
    __syncthreads();
    for (int d = t; d < NN; d += 256) {
        int b = deg[d]; b = b > 255 ? 255 : b;
        int p = atomicAdd(&bins[b], 1);
        dorder[base[b] + p] = d;
    }
}

// scatter + gaussian window: 8 rows, EVEN-aligned k0; gtab packed bf16 pairs (16B)
__global__ void k_scatter(const int* __restrict__ ei, const float* __restrict__ ev,
                          int* __restrict__ fill, int* __restrict__ srcp,
                          float4* __restrict__ evp, int* __restrict__ kptab,
                          unsigned* __restrict__ gtab) {
    int e = blockIdx.x * 256 + threadIdx.x;
    if (e >= EE) return;
    int d = ei[EE + e];
    int pos = atomicAdd(&fill[d], 1);
    float4 e4 = ((const float4*)ev)[e];
    srcp[pos] = ei[e];
    evp[pos] = e4;
    const float step = 12.0f / 127.0f;
    const float coeff = -0.5f / (step * step);
    float dist = e4.w;
    int k0 = ((int)floorf(dist / step) - 3) & ~1;   // even-aligned
    k0 = k0 < 0 ? 0 : (k0 > 120 ? 120 : k0);
    float g[8];
#pragma unroll
    for (int k = 0; k < 8; ++k) {
        float t = dist - (k0 + k) * step;
        g[k] = expf(coeff * t * t);
    }
    kptab[pos] = k0 >> 1;
    unsigned g0 = (unsigned)f2b(g[0]) | ((unsigned)f2b(g[1]) << 16);
    unsigned g1 = (unsigned)f2b(g[2]) | ((unsigned)f2b(g[3]) << 16);
    unsigned g2 = (unsigned)f2b(g[4]) | ((unsigned)f2b(g[5]) << 16);
    unsigned g3 = (unsigned)f2b(g[6]) | ((unsigned)f2b(g[7]) << 16);
    ((uint4*)gtab)[pos] = make_uint4(g0, g1, g2, g3);
}

// ---------------- bf16 MFMA GEMM: C = act(A[M,K] @ BT[N,K]^T + bias) ----------------
template <int OUT_BF16, int ACT>
__global__ __launch_bounds__(256) void k_gemm(
    const u16* __restrict__ A, const u16* __restrict__ BT,
    const float* __restrict__ bias, void* __restrict__ C, int M, int K, int N) {
    __shared__ u16 As[4096];   // [128 rows][32 k] bf16 = 8 KB
    __shared__ u16 Bs[4096];
    int tid = threadIdx.x;
    int wave = tid >> 6, lane = tid & 63;
    int bm = blockIdx.y * 128, bn = blockIdx.x * 128;
    int wm = (wave >> 1) * 64, wn = (wave & 1) * 64;
    int lm = lane & 15;
    int kg = lane >> 4;
    f32x4 acc[4][4] = {};

    for (int k0 = 0; k0 < K; k0 += 32) {
#pragma unroll
        for (int it = 0; it < 2; ++it) {
            int idx = it * 256 + tid;
            int r = idx >> 2, seg = idx & 3;
#ifdef HAVE_GLL
            __builtin_amdgcn_global_load_lds(
                (const unsigned*)&A[(size_t)(bm + r) * K + k0 + seg * 8],
                (unsigned*)&As[idx * 8], 16, 0, 0);
            __builtin_amdgcn_global_load_lds(
                (const unsigned*)&BT[(size_t)(bn + r) * K + k0 + seg * 8],
                (unsigned*)&Bs[idx * 8], 16, 0, 0);
#else
            *(uint4*)&As[idx * 8] = *(const uint4*)&A[(size_t)(bm + r) * K + k0 + seg * 8];
            *(uint4*)&Bs[idx * 8] = *(const uint4*)&BT[(size_t)(bn + r) * K + k0 + seg * 8];
#endif
        }
        __syncthreads();
        bf16x8 af[4], bfr[4];
#pragma unroll
        for (int i = 0; i < 4; ++i)
            af[i] = *(const bf16x8*)&As[(wm + i * 16 + lm) * 32 + kg * 8];
#pragma unroll
        for (int j = 0; j < 4; ++j)
            bfr[j] = *(const bf16x8*)&Bs[(wn + j * 16 + lm) * 32 + kg * 8];
#pragma unroll
        for (int i = 0; i < 4; ++i)
#pragma unroll
            for (int j = 0; j < 4; ++j)
                acc[i][j] = __builtin_amdgcn_mfma_f32_16x16x32_bf16(af[i], bfr[j], acc[i][j], 0, 0, 0);
        __syncthreads();
    }

#pragma unroll
    for (int j = 0; j < 4; ++j) {
        int col = bn + wn + j * 16 + lm;
        float bv = bias ? bias[col] : 0.f;
#pragma unroll
        for (int i = 0; i < 4; ++i) {
            int row0 = bm + wm + i * 16 + kg * 4;
#pragma unroll
            for (int r = 0; r < 4; ++r) {
                float v = acc[i][j][r] + bv;
                if (ACT) v = silu(v);
                if (OUT_BF16)
                    ((u16*)C)[(size_t)(row0 + r) * N + col] = f2b(v);
                else
                    ((float*)C)[(size_t)(row0 + r) * N + col] = v;
            }
        }
    }
}

// ---------------- fused message pass: pair-panel + fdot2; bf16-only vec output -----
__global__ __launch_bounds__(1024) void k_msg(
    const u16* __restrict__ xhb, const u16* __restrict__ vinb,
    const int* __restrict__ srcp, const float4* __restrict__ evp,
    const int* __restrict__ row_ptr, const int* __restrict__ kptab,
    const unsigned* __restrict__ gtab, const u16* __restrict__ WP /*pair-interleaved*/,
    const float* __restrict__ rbias, float* __restrict__ x,
    const float* __restrict__ vin, u16* __restrict__ vecMb,
    const int* __restrict__ dorder) {
    __shared__ u16 Wp[64 * 512];    // 64 KB: [64 row-pairs][256 cols][2]
    int tid = threadIdx.x;
    int wave = tid >> 6, lane = tid & 63;
    int c0 = lane * 4;
    int d = dorder[blockIdx.x * MSG_WAVES + wave];
    int E0 = row_ptr[d], E1 = row_ptr[d + 1];
    float accv[3][4] = {};          // persists across panels 1,2

#pragma unroll
    for (int p = 0; p < 3; ++p) {
        __syncthreads();
#pragma unroll
        for (int it = 0; it < 4; ++it) {        // cooperative 64KB panel load
            int idx = it * 1024 + tid;          // 4096 uint4
            int r = idx >> 6;                   // 64 row-pairs, 64 uint4/pair
            int c8 = (idx & 63) * 8;
            *(uint4*)&Wp[r * 512 + c8] =
                *(const uint4*)&WP[(size_t)r * 1536 + p * 512 + c8];
        }
        __syncthreads();
        float4 bb = ((const float4*)(rbias + p * 256))[lane];
        float bias4[4] = {bb.x, bb.y, bb.z, bb.w};
        float accx[4] = {};
        for (int j = E0; j < E1; ++j) {
            int s = srcp[j];
            int kp = kptab[j];
            uint4 gt = ((const uint4*)gtab)[j];
            unsigned gp[4] = {gt.x, gt.y, gt.z, gt.w};
            float rr[4] = {bias4[0], bias4[1], bias4[2], bias4[3]};
#pragma unroll
            for (int p2 = 0; p2 < 4; ++p2) {
                U8 w;
                w.v = *(const uint4*)&Wp[(kp + p2) * 512 + c0 * 2];  // ds_read_b128
#ifdef HAVE_FDOT2
                BU gv; gv.u = gp[p2];
#pragma unroll
                for (int c = 0; c < 4; ++c) {
                    BU wv; wv.u = w.w[c];
                    rr[c] = __builtin_amdgcn_fdot2_f32_bf16(wv.v, gv.v, rr[c], false);
                }
#else
                float ge = b2f((u16)(gp[p2] & 0xffff));
                float go = b2f((u16)(gp[p2] >> 16));
#pragma unroll
                for (int c = 0; c < 4; ++c)
                    rr[c] += ge * b2f(w.a[2 * c]) + go * b2f(w.a[2 * c + 1]);
#endif
            }
            if (p == 0) {
                U4 X; X.v = *(const ushort4*)(xhb + (size_t)s * 768 + c0);
#pragma unroll
                for (int c = 0; c < 4; ++c) accx[c] += b2f(X.a[c]) * rr[c];
            } else if (p == 1) {
                U4 X, V0, V1, V2;
                X.v = *(const ushort4*)(xhb + (size_t)s * 768 + 256 + c0);
                V0.v = *(const ushort4*)(vinb + (size_t)s * 768 + c0);
                V1.v = *(const ushort4*)(vinb + (size_t)s * 768 + 256 + c0);
                V2.v = *(const ushort4*)(vinb + (size_t)s * 768 + 512 + c0);
#pragma unroll
                for (int c = 0; c < 4; ++c) {
                    float m1 = b2f(X.a[c]) * rr[c] * kInvSqrt3;
                    accv[0][c] += b2f(V0.a[c]) * m1;
                    accv[1][c] += b2f(V1.a[c]) * m1;
                    accv[2][c] += b2f(V2.a[c]) * m1;
                }
            } else {
                U4 X; X.v = *(const ushort4*)(xhb + (size_t)s * 768 + 512 + c0);
                float4 ev4 = evp[j];
#pragma unroll
                for (int c = 0; c < 4; ++c) {
                    float m2 = b2f(X.a[c]) * rr[c];
                    accv[0][c] += m2 * ev4.x;
                    accv[1][c] += m2 * ev4.y;
                    accv[2][c] += m2 * ev4.z;
                }
            }
        }
        if (p == 0) {
            size_t xi = (size_t)d * 256 + c0;
            float4 xv = *(const float4*)&x[xi];
            xv.x = (xv.x + accx[0]) * kInvSqrt2;
            xv.y = (xv.y + accx[1]) * kInvSqrt2;
            xv.z = (xv.z + accx[2]) * kInvSqrt2;
            xv.w = (xv.w + accx[3]) * kInvSqrt2;
            *(float4*)&x[xi] = xv;
        }
    }
    // epilogue: vecM(bf16) = vin + dvec * invSqrtH
#pragma unroll
    for (int k = 0; k < 3; ++k) {
        size_t idx = (size_t)d * 768 + k * 256 + c0;
        float4 vv = *(const float4*)&vin[idx];
        ushort4 u;
        u.x = f2b(vv.x + accv[k][0] * kInvSqrtH);
        u.y = f2b(vv.y + accv[k][1] * kInvSqrtH);
        u.z = f2b(vv.z + accv[k][2] * kInvSqrtH);
        u.w = f2b(vv.w + accv[k][3] * kInvSqrtH);
        *(ushort4*)&vecMb[idx] = u;
    }
}

// ---------------- vec_dot + hcat(bf16) = [x, vnorm]; vp in bf16 -------------------
__global__ void k_vecdot(const u16* __restrict__ vp, const float* __restrict__ x,
                         float* __restrict__ vec_dot, u16* __restrict__ hcat) {
    int i = blockIdx.x * 256 + threadIdx.x;  // N*H
    int n = i >> 8, c = i & 255;
    const u16* p = vp + (size_t)n * 1536;
    float dsum = 0.f, qsum = 0.f;
#pragma unroll
    for (int k = 0; k < 3; ++k) {
        float v1 = b2f(p[k * 512 + c]);
        float v2 = b2f(p[k * 512 + 256 + c]);
        dsum += v1 * v2;
        qsum += v2 * v2;
    }
    vec_dot[i] = dsum * kInvSqrtH;
    hcat[(size_t)n * 512 + c] = f2b(x[i]);
    hcat[(size_t)n * 512 + 256 + c] = f2b(sqrtf(qsum + 1e-8f));
}

// ---------------- update epilogue + fused LayerNorm; vecM read as bf16 -------------
__global__ void k_update_out(const u16* __restrict__ hout, const float* __restrict__ vec_dot,
                             const u16* __restrict__ vp, float* __restrict__ x,
                             const u16* __restrict__ vecMb, float* __restrict__ vfin,
                             u16* __restrict__ vb,
                             const float* __restrict__ lnw, const float* __restrict__ lnb,
                             u16* __restrict__ xout) {
    int n = blockIdx.x, t = threadIdx.x;
    size_t i = (size_t)n * 256 + t;
    float xv1 = b2f(hout[(size_t)n * 768 + t]);
    float xv2 = b2f(hout[(size_t)n * 768 + 256 + t]);
    float xv3 = b2f(hout[(size_t)n * 768 + 512 + t]);
    float dxv = (xv1 + xv2 * vec_dot[i]) * kInvSqrt2;
    float nx = (x[i] + dxv) * kInvSqrt2;
    x[i] = nx;
#pragma unroll
    for (int k = 0; k < 3; ++k) {
        size_t idx = (size_t)n * 768 + k * 256 + t;
        float nv = b2f(vecMb[idx]) + xv3 * b2f(vp[(size_t)n * 1536 + k * 512 + t]);
        vfin[idx] = nv;
        vb[idx] = f2b(nv);
    }
    if (lnw) {
        float s = nx, q = nx * nx;
#pragma unroll
        for (int m = 32; m >= 1; m >>= 1) {
            s += __shfl_xor(s, m, 64);
            q += __shfl_xor(q, m, 64);
        }
        __shared__ float s_sum[4], s_sq[4];
        int wid = t >> 6;
        if ((t & 63) == 0) { s_sum[wid] = s; s_sq[wid] = q; }
        __syncthreads();
        float S = s_sum[0] + s_sum[1] + s_sum[2] + s_sum[3];
        float Q = s_sq[0] + s_sq[1] + s_sq[2] + s_sq[3];
        float mu = S * (1.0f / HH);
        float var = Q * (1.0f / HH) - mu * mu;
        float rs = rsqrtf(var + 1e-5f);
        xout[i] = f2b((nx - mu) * rs * lnw[t] + lnb[t]);
    } else {
        xout[i] = f2b(nx);
    }
}

// ---------------- energy reduce ----------------
__global__ void k_energy2(const float* __restrict__ h, const float* __restrict__ w2,
                          const float* __restrict__ b2, const int* __restrict__ batch,
                          float* __restrict__ out) {
    __shared__ float g[NGG];
    int t = threadIdx.x;
    if (t < NGG) g[t] = 0.f;
    __syncthreads();
    int a = blockIdx.x * 256 + t;
    const float4* hr = (const float4*)(h + (size_t)a * 128);
    const float4* w4 = (const float4*)w2;
    float acc = 0.f;
#pragma unroll 8
    for (int i = 0; i < 32; ++i) {
        float4 hv = hr[i], wv = w4[i];
        acc += hv.x * wv.x + hv.y * wv.y + hv.z * wv.z + hv.w * wv.w;
    }
    acc += b2[0];
    atomicAdd(&g[batch[a]], acc);
    __syncthreads();
    if (t < NGG && g[t] != 0.f) atomicAdd(&out[t], g[t]);
}

extern "C" void kernel_launch(void* const* d_in, const int* in_sizes, int n_in,
                              void* d_out, int out_size, void* d_ws, size_t ws_size,
                              hipStream_t stream) {
    const float* pos      = (const float*)d_in[0];
    const float* atom_emb = (const float*)d_in[1];
    const float* ln_w     = (const float*)d_in[2];
    const float* ln_b     = (const float*)d_in[3];
    const float* xp_w1    = (const float*)d_in[4];
    const float* xp_b1    = (const float*)d_in[5];
    const float* xp_w2    = (const float*)d_in[6];
    const float* xp_b2    = (const float*)d_in[7];
    const float* rbf_w    = (const float*)d_in[8];
    const float* rbf_b    = (const float*)d_in[9];
    const float* vec_w    = (const float*)d_in[10];
    const float* xv_w1    = (const float*)d_in[11];
    const float* xv_b1    = (const float*)d_in[12];
    const float* xv_w2    = (const float*)d_in[13];
    const float* xv_b2    = (const float*)d_in[14];
    const float* oe_w1    = (const float*)d_in[15];
    const float* oe_b1    = (const float*)d_in[16];
    const float* oe_w2    = (const float*)d_in[17];
    const float* oe_b2    = (const float*)d_in[18];
    const int*   z        = (const int*)d_in[19];
    const int*   ei       = (const int*)d_in[20];
    const int*   batch    = (const int*)d_in[21];
    float* out = (float*)d_out;

    char* ws = (char*)d_ws;
    size_t off = 0;
    auto alloc = [&](size_t b) {
        void* p = ws + off;
        off = (off + b + 255) & ~(size_t)255;
        return p;
    };
    float*    x      = (float*)alloc((size_t)NN * HH * 4);       //   8 MB
    float*    vecA   = (float*)alloc((size_t)NN * 768 * 4);      //  24 MB  \ adjacent:
    u16*      vb     = (u16*)alloc((size_t)NN * 768 * 2);        //  12 MB  / joint zero
    u16*      vecMb  = (u16*)alloc((size_t)NN * 768 * 2);        //  12 MB
    u16*      xlnb   = (u16*)alloc((size_t)NN * HH * 2);         //   4 MB (alias xb)
    u16*      t1b    = (u16*)alloc((size_t)NN * HH * 2);         //   4 MB (alias h1b)
    u16*      xhb    = (u16*)alloc((size_t)NN * 768 * 2);        //  12 MB (alias hcatb)
    float*    vdot   = (float*)alloc((size_t)NN * HH * 4);       //   8 MB (alias heng)
    u16*      vpb    = (u16*)alloc((size_t)NN * 1536 * 2);       //  24 MB
    u16*      houtb  = (u16*)alloc((size_t)NN * 768 * 2);        //  12 MB
    float*    ev     = (float*)alloc((size_t)EE * 4 * 4);        //   2 MB
    int*      deg    = (int*)alloc((size_t)NN * 4);
    int*      row_ptr= (int*)alloc((size_t)(NN + 1) * 4);
    int*      fill   = (int*)alloc((size_t)NN * 4);
    int*      dorder = (int*)alloc((size_t)NN * 4);
    int*      srcp   = (int*)alloc((size_t)EE * 4);
    float4*   evp    = (float4*)alloc((size_t)EE * 16);          //   2 MB
    int*      kptab  = (int*)alloc((size_t)EE * 4);              // 0.5 MB
    unsigned* gtab   = (unsigned*)alloc((size_t)EE * 16);        //   2 MB (bf16 pairs)
    u16* xp_w1T   = (u16*)alloc((size_t)3 * 256 * 256 * 2);
    u16* xp_w2T   = (u16*)alloc((size_t)3 * 768 * 256 * 2);
    u16* rbf_wP   = (u16*)alloc((size_t)3 * 128 * 768 * 2);      // pair-interleaved bf16
    u16* vec_wT   = (u16*)alloc((size_t)3 * 512 * 256 * 2);
    u16* xv_w1T   = (u16*)alloc((size_t)3 * 256 * 512 * 2);
    u16* xv_w2T   = (u16*)alloc((size_t)3 * 768 * 256 * 2);
    u16* oe_w1T   = (u16*)alloc((size_t)128 * 256 * 2);
    (void)ws_size;

    u16*   h1b   = t1b;
    u16*   hcatb = xhb;
    float* heng  = vdot;
    u16*   xb    = xlnb;

    // ---- setup ----
    k_wt_all<<<2432, 256, 0, stream>>>(xp_w1, xp_w2, rbf_w, vec_w, xv_w1, xv_w2, oe_w1,
                                       xp_w1T, xp_w2T, rbf_wP, vec_wT, xv_w1T, xv_w2T, oe_w1T);
    k_zero<<<(36 * 1024 * 1024 / 16 + 255) / 256, 256, 0, stream>>>(vecA, 36 * 1024 * 1024 / 16);
    k_zero<<<8, 256, 0, stream>>>((float*)deg, NN / 4);
    k_init_ln<<<NN, 256, 0, stream>>>(atom_emb, z, ln_w, ln_b, x, xlnb);
    k_geom_hist<<<EE / 256, 256, 0, stream>>>(pos, ei, ev, deg);
    k_scan_sort<<<1, 256, 0, stream>>>(deg, row_ptr, fill, dorder);
    k_scatter<<<EE / 256, 256, 0, stream>>>(ei, ev, fill, srcp, evp, kptab, gtab);

    for (int l = 0; l < LL; ++l) {
        // ---- PaiNNMessage ----
        k_gemm<1, 1><<<dim3(2, NN / 128), 256, 0, stream>>>(
            xlnb, xp_w1T + (size_t)l * 256 * 256, xp_b1 + l * HH, t1b, NN, 256, 256);
        k_gemm<1, 0><<<dim3(6, NN / 128), 256, 0, stream>>>(
            t1b, xp_w2T + (size_t)l * 768 * 256, xp_b2 + l * 768, xhb, NN, 256, 768);
        k_msg<<<NN / MSG_WAVES, 1024, 0, stream>>>(
            xhb, vb, srcp, evp, row_ptr, kptab, gtab,
            rbf_wP + (size_t)l * 128 * 768, rbf_b + l * 768, x, vecA, vecMb, dorder);

        // ---- PaiNNUpdate ----
        k_gemm<1, 0><<<dim3(4, 3 * NN / 128), 256, 0, stream>>>(
            vecMb, vec_wT + (size_t)l * 512 * 256, nullptr, vpb, 3 * NN, 256, 512);
        k_vecdot<<<NN, 256, 0, stream>>>(vpb, x, vdot, hcatb);
        k_gemm<1, 1><<<dim3(2, NN / 128), 256, 0, stream>>>(
            hcatb, xv_w1T + (size_t)l * 256 * 512, xv_b1 + l * HH, h1b, NN, 512, 256);
        k_gemm<1, 0><<<dim3(6, NN / 128), 256, 0, stream>>>(
            h1b, xv_w2T + (size_t)l * 768 * 256, xv_b2 + l * 768, houtb, NN, 256, 768);
        bool last = (l == LL - 1);
        k_update_out<<<NN, 256, 0, stream>>>(
            houtb, vdot, vpb, x, vecMb, vecA, vb,
            last ? nullptr : ln_w + (l + 1) * HH,
            last ? nullptr : ln_b + (l + 1) * HH, xlnb);
    }

    // ---- energy head ----
    k_gemm<0, 1><<<dim3(1, NN / 128), 256, 0, stream>>>(
        xb, oe_w1T, oe_b1, heng, NN, 256, 128);
    k_zero<<<1, 256, 0, stream>>>(out, NGG / 4);
    k_energy2<<<32, 256, 0, stream>>>(heng, oe_w2, oe_b2, batch, out);
}